// Round 10
// baseline (382.389 us; speedup 1.0000x reference)
//
#include <hip/hip_runtime.h>

#define NBATCH 32
#define NFEAT 48
#define C1c 6
#define LRC 42
#define HH 128
#define WW 128
#define HWSZ 16384
#define NP 81
#define NQ 64

// workspace layout (in floats)
#define OFF_PM   0                      // 81*64 = 5184
#define OFF_GAP  5184                   // 32*42 = 1344  (contiguous after PM)
#define OFF_K    6528                   // 64*64 = 4096
#define OFF_ATTN 10624                  // 1344
#define OFF_WB   11968                  // 48*48 = 2304 rearranged weights
#define OFF_HR   14272                  // 32*6*16384 = 3145728

// ---------------- K1a: softmax denominators -> inv (in d_out scratch); also zero pm+gap ----------
// float2 per thread, 1024 blocks -> 4 blocks/CU, 16 waves/CU (2x r9's latency hiding).
__global__ __launch_bounds__(256) void k_sm1(const float* __restrict__ logits,
                                             float* __restrict__ invbuf,
                                             float* __restrict__ zbuf) {
    int idx = blockIdx.x * 256 + threadIdx.x;     // 0..262143 (float2 index)
    if (idx < NP * NQ + NBATCH * LRC) zbuf[idx] = 0.f;
    int b   = idx >> 13;                          // 8192 float2 per batch image
    int pos = (idx & 8191) << 1;
    const float* base = logits + (((size_t)b * NP) << 14) + pos;
    float s0 = 0.f, s1 = 0.f;
    for (int p = 0; p < NP; ++p) {
        float2 v = *(const float2*)&base[(size_t)p << 14];
        s0 += __expf(v.x); s1 += __expf(v.y);
    }
    *(float2*)&invbuf[(size_t)idx << 1] = make_float2(1.f / s0, 1.f / s1);
}

// ---------------- K1b: binning pass -> pm_sum[81][64] ----------------
__global__ __launch_bounds__(256) void k_sm2(const float* __restrict__ logits,
                                             const float* __restrict__ invbuf,
                                             float* __restrict__ pm_sum) {
    int bid = blockIdx.x;                 // b*81 + p
    int b = bid / NP, p = bid - b * NP;
    const float* base = logits + ((size_t)(b * NP + p) << 14);
    const float* ib   = invbuf + ((size_t)b << 14);
    int tid = threadIdx.x;
    int r0 = tid >> 5, xt = tid & 31;
    float a0 = 0.f, a1 = 0.f, a2 = 0.f, a3 = 0.f;
    int off = (r0 << 7) + (xt << 2);
    for (int k = 0; k < 16; ++k, off += 1024) {
        float4 l4 = *(const float4*)&base[off];
        float4 i4 = *(const float4*)&ib[off];
        a0 += __expf(l4.x) * i4.x;
        a1 += __expf(l4.y) * i4.y;
        a2 += __expf(l4.z) * i4.z;
        a3 += __expf(l4.w) * i4.w;
    }
#pragma unroll
    for (int m = 2; m <= 16; m <<= 1) {
        a0 += __shfl_xor(a0, m); a1 += __shfl_xor(a1, m);
        a2 += __shfl_xor(a2, m); a3 += __shfl_xor(a3, m);
    }
    if (xt < 2) {
        int qb = p * NQ + (r0 << 3) + ((xt & 1) << 2);
        atomicAdd(&pm_sum[qb + 0], a0);
        atomicAdd(&pm_sum[qb + 1], a1);
        atomicAdd(&pm_sum[qb + 2], a2);
        atomicAdd(&pm_sum[qb + 3], a3);
    }
}

// ---------------- K2: gap sums + 1x1 base + biases + up(ms) -> out ----------------
__global__ __launch_bounds__(256) void k_base(const float* __restrict__ feat,
                                              const float* __restrict__ ms,
                                              const float* __restrict__ w_res,
                                              const float* __restrict__ b_fine,
                                              const float* __restrict__ b_res,
                                              float* __restrict__ gap,
                                              float* __restrict__ out) {
    int gid = blockIdx.x;
    int b = gid >> 4, strip = gid & 15;
    int tid = threadIdx.x;
    int row = (strip << 3) + (tid >> 5);
    int x0  = (tid & 31) << 2;
    int poff = (row << 7) + x0;
    int lane = tid & 63;
    const float* fb = feat + (((size_t)b * NFEAT) << 14);
    float a[4][4];
#pragma unroll
    for (int j = 0; j < 4; ++j)
#pragma unroll
        for (int o = 0; o < 4; ++o) a[j][o] = 0.f;
    for (int c = 0; c < NFEAT; ++c) {
        float4 f = *(const float4*)&fb[((size_t)c << 14) + poff];
        float wr0 = w_res[c], wr1 = w_res[NFEAT + c];
        float wr2 = w_res[2 * NFEAT + c], wr3 = w_res[3 * NFEAT + c];
        a[0][0] += wr0 * f.x; a[0][1] += wr1 * f.x; a[0][2] += wr2 * f.x; a[0][3] += wr3 * f.x;
        a[1][0] += wr0 * f.y; a[1][1] += wr1 * f.y; a[1][2] += wr2 * f.y; a[1][3] += wr3 * f.y;
        a[2][0] += wr0 * f.z; a[2][1] += wr1 * f.z; a[2][2] += wr2 * f.z; a[2][3] += wr3 * f.z;
        a[3][0] += wr0 * f.w; a[3][1] += wr1 * f.w; a[3][2] += wr2 * f.w; a[3][3] += wr3 * f.w;
        if (c >= C1c) {
            float s = (f.x + f.y) + (f.z + f.w);
            s += __shfl_xor(s, 1);  s += __shfl_xor(s, 2);  s += __shfl_xor(s, 4);
            s += __shfl_xor(s, 8);  s += __shfl_xor(s, 16); s += __shfl_xor(s, 32);
            if (lane == 0) atomicAdd(&gap[b * LRC + (c - C1c)], s);
        }
    }
    float syf = (row + 0.5f) * 0.25f - 0.5f;
    int y0i = (int)floorf(syf); float fy = syf - (float)y0i;
    int y0c = min(31, max(0, y0i)), y1c = min(31, max(0, y0i + 1));
    float fxv[4]; int x0v[4], x1v[4];
#pragma unroll
    for (int j = 0; j < 4; ++j) {
        float sxf = (x0 + j + 0.5f) * 0.25f - 0.5f;
        int x0i = (int)floorf(sxf);
        fxv[j] = sxf - (float)x0i;
        x0v[j] = min(31, max(0, x0i));
        x1v[j] = min(31, max(0, x0i + 1));
    }
#pragma unroll
    for (int o = 0; o < 4; ++o) {
        const float* mb = ms + ((size_t)(b * 4 + o) << 10);
        float addc = b_fine[o] + b_res[o];
        float res[4];
#pragma unroll
        for (int j = 0; j < 4; ++j) {
            float m00 = mb[(y0c << 5) + x0v[j]], m01 = mb[(y0c << 5) + x1v[j]];
            float m10 = mb[(y1c << 5) + x0v[j]], m11 = mb[(y1c << 5) + x1v[j]];
            float up = (m00 * (1.f - fxv[j]) + m01 * fxv[j]) * (1.f - fy)
                     + (m10 * (1.f - fxv[j]) + m11 * fxv[j]) * fy;
            res[j] = a[j][o] + addc + up;
        }
        *(float4*)&out[(((size_t)(b * 4 + o)) << 14) + poff] =
            make_float4(res[0], res[1], res[2], res[3]);
    }
}

// ---------------- K3: build K (64x64), attn (32x42), and rearranged weights wbuf[48][48] ----------------
__global__ __launch_bounds__(256) void k_small(const float* __restrict__ pm_sum,
                                               const float* __restrict__ gap_sum,
                                               const float* __restrict__ sigx,
                                               const float* __restrict__ sigy,
                                               const float* __restrict__ opac,
                                               const float* __restrict__ rho,
                                               const float* __restrict__ w_v2,
                                               const float* __restrict__ w_fine,
                                               const float* __restrict__ w_res,
                                               float* __restrict__ Kmat,
                                               float* __restrict__ attn,
                                               float* __restrict__ wbuf) {
    int tid = threadIdx.x;
    if (tid < 64) {
        int q = tid;
        float wsx = 0.f, wsy = 0.f, wop = 0.f, wr = 0.f;
        for (int p = 0; p < NP; ++p) {
            float pv = pm_sum[p * NQ + q] * (1.f / 8192.f);
            wsx += sigx[p] * pv;
            wsy += sigy[p] * pv;
            wop += opac[p] * pv;
            wr  += rho[p]  * pv;
        }
        float a = wsx * wsx, d = wsy * wsy, bc = wr * wsx * wsy;
        float det = a * d - bc * bc;
        float i00 = d / det, i01 = -bc / det, i11 = a / det;
        int iq = q >> 3, jq = q & 7;
        for (int h = 0; h < 8; ++h)
            for (int w = 0; w < 8; ++w) {
                int ki = h - iq + 2, kj = w - jq + 2;
                float val = 0.f;
                if (ki >= 0 && ki < 5 && kj >= 0 && kj < 5) {
                    float xx = -5.f + 2.5f * ki, yy = -5.f + 2.5f * kj;
                    val = wop * __expf(-0.5f * (i00 * xx * xx + 2.f * i01 * xx * yy + i11 * yy * yy));
                }
                Kmat[(q << 6) + (h << 3) + w] = val;
            }
    }
    for (int i = tid; i < NBATCH * LRC; i += 256) {
        int b = i / LRC, co = i % LRC;
        float s = 0.f;
        for (int ci = 0; ci < LRC; ++ci) s += w_v2[co * LRC + ci] * gap_sum[b * LRC + ci];
        s *= (1.f / 16384.f);
        attn[i] = 1.f / (1.f + __expf(-s));
    }
    for (int i = tid; i < NFEAT * 48; i += 256) {
        int c = i / 48, j = i - c * 48;
        float v = 0.f;
        if (j < 36) v = w_fine[(j / 9) * (NFEAT * 9) + c * 9 + (j % 9)];
        else if (j < 40) v = w_res[(j - 36) * NFEAT + c];
        wbuf[i] = v;
    }
}

// ---------------- K4: hr = (colors @ K) * V1 ----------------
__global__ __launch_bounds__(256) void k_hr(const float* __restrict__ feat,
                                            const float* __restrict__ V,
                                            const float* __restrict__ Kmat,
                                            float* __restrict__ hrbuf) {
    __shared__ __align__(16) float lK[4096];          // [q][pos] packed; reads broadcast
    __shared__ __align__(16) float lF[2 * 16 * 128];
    int bid = blockIdx.x;
    int b   = bid / 24;
    int r   = bid - b * 24;
    int strip = r / 3;
    int ch  = (r - strip * 3) * 2;
    int y0  = strip << 4;
    int tid = threadIdx.x;
    {
        const float4* ks = (const float4*)Kmat;
        float4* kd = (float4*)lK;
        for (int i = tid; i < 1024; i += 256) kd[i] = ks[i];
        float4* fd = (float4*)lF;
        const float* fb = feat + (((size_t)b * NFEAT + ch) << 14) + (y0 << 7);
        for (int i = tid; i < 1024; i += 256) {
            int c = i >> 9, rem = i & 511;
            fd[i] = *(const float4*)&fb[((size_t)c << 14) + (rem << 2)];
        }
    }
    __syncthreads();
    int tile = tid >> 3, hrow = tid & 7;
    int tr = tile >> 4, tx = tile & 15;
    float acc[2][8];
#pragma unroll
    for (int c = 0; c < 2; ++c)
#pragma unroll
        for (int j = 0; j < 8; ++j) acc[c][j] = 0.f;
    int fbase = (tr << 3) * 128 + (tx << 3);
    for (int q = 0; q < 64; ++q) {
        int iq = q >> 3, jq = q & 7;
        const float4 k0 = *(const float4*)&lK[(q << 6) + (hrow << 3)];
        const float4 k1 = *(const float4*)&lK[(q << 6) + (hrow << 3) + 4];
#pragma unroll
        for (int c = 0; c < 2; ++c) {
            float col = lF[(c << 11) + fbase + (iq << 7) + jq];
            acc[c][0] += col * k0.x; acc[c][1] += col * k0.y;
            acc[c][2] += col * k0.z; acc[c][3] += col * k0.w;
            acc[c][4] += col * k1.x; acc[c][5] += col * k1.y;
            acc[c][6] += col * k1.z; acc[c][7] += col * k1.w;
        }
    }
    int y = y0 + (tr << 3) + hrow;
#pragma unroll
    for (int c = 0; c < 2; ++c) {
        const float4* vp = (const float4*)(V + (((size_t)b * NFEAT + ch + c) << 14) + ((size_t)y << 7) + (tx << 3));
        float4 v0 = vp[0], v1 = vp[1];
        float4 r0, r1;
        r0.x = acc[c][0] * v0.x; r0.y = acc[c][1] * v0.y; r0.z = acc[c][2] * v0.z; r0.w = acc[c][3] * v0.w;
        r1.x = acc[c][4] * v1.x; r1.y = acc[c][5] * v1.y; r1.z = acc[c][6] * v1.z; r1.w = acc[c][7] * v1.w;
        float4* op = (float4*)(hrbuf + (((size_t)b * C1c + ch + c) << 14) + ((size_t)y << 7) + (tx << 3));
        op[0] = r0; op[1] = r1;
    }
}

// ---------------- K5: conv3x3 (RMW onto 1x1 base), SOFTWARE-PIPELINED staging ----------------
// r9 shell (16x32 tile, 2px vertical pair, conflict-free mapping, grid 1024 XCD-swizzled)
// + T14 async-STAGE: chunk cb+1's global loads prefetched into regs, issued before compute(cb).
#define CCH 8
__global__ __launch_bounds__(256, 4) void k_conv(const float* __restrict__ feat,
                                                 const float* __restrict__ V,
                                                 const float* __restrict__ wbuf,
                                                 const float* __restrict__ hrbuf,
                                                 const float* __restrict__ attn,
                                                 float* __restrict__ out) {
    __shared__ float s_in[CCH][18 * 40];   // lds row = input row + 1; lds col = input col + 4
    int bid0 = blockIdx.x;
    int rid  = (bid0 & 7) * 128 + (bid0 >> 3);    // bijective XCD swizzle (1024 = 8*128)
    int b    = rid >> 5;
    int t32  = rid & 31;
    int ty0  = (t32 >> 2) << 4;
    int tx0  = (t32 & 3) << 5;
    int tid  = threadIdx.x;
    int rp   = tid >> 5;                  // 0..7 (row pair)
    int j    = tid & 31;                  // col 0..31
    int gx   = tx0 + j;
    int gy0  = ty0 + 2 * rp;
    int own_g0 = (gy0 << 7) + gx;
    int own_g1 = own_g0 + 128;
    int own_l0 = (2 * rp + 1) * 40 + 4 + j;
    int own_l1 = own_l0 + 40;

    // halo ring: 100 positions (top 34, bottom 34, left 16, right 16)
    bool hhas = tid < 100;
    int rr, cc;
    if (tid < 34)      { rr = 0;        cc = tid; }
    else if (tid < 68) { rr = 17;       cc = tid - 34; }
    else if (tid < 84) { rr = tid - 67; cc = 0; }
    else               { rr = tid - 83; cc = 33; }
    int hsy = ty0 - 1 + rr, hsx = tx0 - 1 + cc;
    float hfm = (hsy >= 0 && hsy < HH && hsx >= 0 && hsx < WW) ? 1.f : 0.f;
    int hoff = (min(HH - 1, max(0, hsy)) << 7) + min(WW - 1, max(0, hsx));
    int hlds = rr * 40 + 3 + cc;

    const float* atb = attn + b * LRC;

    // prefetch registers (statically indexed via unrolled loops -> stay in VGPRs)
    float pA0[CCH], pB0[CCH], pA1[CCH], pB1[CCH], pAh[CCH], pBh[CCH], amv[CCH];

#define LOADC(CB)                                                               \
    {                                                                           \
        _Pragma("unroll")                                                       \
        for (int k = 0; k < CCH; ++k) {                                         \
            int c = (CB) + k;                                                   \
            if (c < C1c) {                                                      \
                const float* hsrc = hrbuf + (((size_t)b * C1c + c) << 14);      \
                pA0[k] = hsrc[own_g0]; pB0[k] = 1.f;                            \
                pA1[k] = hsrc[own_g1]; pB1[k] = 1.f;                            \
                pAh[k] = hhas ? hsrc[hoff] : 0.f; pBh[k] = 1.f;                 \
                amv[k] = 1.f;                                                   \
            } else {                                                            \
                const float* fsrc = feat + (((size_t)b * NFEAT + c) << 14);     \
                const float* vsrc = V    + (((size_t)b * NFEAT + c) << 14);     \
                pA0[k] = fsrc[own_g0]; pB0[k] = vsrc[own_g0];                   \
                pA1[k] = fsrc[own_g1]; pB1[k] = vsrc[own_g1];                   \
                pAh[k] = hhas ? fsrc[hoff] : 0.f;                               \
                pBh[k] = hhas ? vsrc[hoff] : 0.f;                               \
                amv[k] = atb[c - C1c];                                          \
            }                                                                   \
        }                                                                       \
    }

    float a00 = 0.f, a01 = 0.f, a02 = 0.f, a03 = 0.f;   // row gy0
    float a10 = 0.f, a11 = 0.f, a12 = 0.f, a13 = 0.f;   // row gy0+1

    LOADC(0);
    for (int cb = 0; cb < NFEAT; cb += CCH) {
        __syncthreads();
        // ---- write prefetched chunk to LDS (waits on its loads here) ----
#pragma unroll
        for (int k = 0; k < CCH; ++k) {
            s_in[k][own_l0] = pA0[k] * pB0[k] * amv[k];
            s_in[k][own_l1] = pA1[k] * pB1[k] * amv[k];
            if (hhas) s_in[k][hlds] = pAh[k] * pBh[k] * (amv[k] * hfm);
        }
        __syncthreads();
        // ---- issue next chunk's loads; latency hides under compute below ----
        if (cb + CCH < NFEAT) LOADC(cb + CCH);
        // ---- compute current chunk (LDS + scalar weights only) ----
        for (int k = 0; k < CCH; ++k) {               // rolled
            int c = cb + k;
            const float* wc = wbuf + c * 48;          // uniform -> s_load
            int base = (2 * rp) * 40 + 3 + j;         // lds row 2rp = input row 2rp-1
            float t00 = s_in[k][base],       t01 = s_in[k][base + 1],   t02 = s_in[k][base + 2];
            float t10 = s_in[k][base + 40],  t11 = s_in[k][base + 41],  t12 = s_in[k][base + 42];
            float t20 = s_in[k][base + 80],  t21 = s_in[k][base + 81],  t22 = s_in[k][base + 82];
            float t30 = s_in[k][base + 120], t31 = s_in[k][base + 121], t32 = s_in[k][base + 122];
#pragma unroll
            for (int o = 0; o < 4; ++o) {
                float w0 = wc[o * 9 + 0], w1 = wc[o * 9 + 1], w2 = wc[o * 9 + 2];
                float w3 = wc[o * 9 + 3], w4 = wc[o * 9 + 4], w5 = wc[o * 9 + 5];
                float w6 = wc[o * 9 + 6], w7 = wc[o * 9 + 7], w8 = wc[o * 9 + 8];
                float r0 = w0 * t00 + w1 * t01 + w2 * t02
                         + w3 * t10 + w4 * t11 + w5 * t12
                         + w6 * t20 + w7 * t21 + w8 * t22;
                float r1 = w0 * t10 + w1 * t11 + w2 * t12
                         + w3 * t20 + w4 * t21 + w5 * t22
                         + w6 * t30 + w7 * t31 + w8 * t32;
                if (o == 0) { a00 += r0; a10 += r1; }
                else if (o == 1) { a01 += r0; a11 += r1; }
                else if (o == 2) { a02 += r0; a12 += r1; }
                else { a03 += r0; a13 += r1; }
            }
        }
    }
#undef LOADC
    // RMW onto the 1x1+bias+ms base
    float ar0[4] = { a00, a01, a02, a03 };
    float ar1[4] = { a10, a11, a12, a13 };
#pragma unroll
    for (int o = 0; o < 4; ++o) {
        float* op0 = out + (((size_t)(b * 4 + o)) << 14) + own_g0;
        float* op1 = out + (((size_t)(b * 4 + o)) << 14) + own_g1;
        *op0 = *op0 + ar0[o];
        *op1 = *op1 + ar1[o];
    }
}

extern "C" void kernel_launch(void* const* d_in, const int* in_sizes, int n_in,
                              void* d_out, int out_size, void* d_ws, size_t ws_size,
                              hipStream_t stream) {
    (void)in_sizes; (void)n_in; (void)out_size; (void)ws_size;
    const float* ms     = (const float*)d_in[0];
    const float* feat   = (const float*)d_in[1];
    const float* V      = (const float*)d_in[2];
    const float* logits = (const float*)d_in[3];
    const float* sigx   = (const float*)d_in[4];
    const float* sigy   = (const float*)d_in[5];
    const float* opac   = (const float*)d_in[6];
    const float* rho    = (const float*)d_in[7];
    const float* w_v2   = (const float*)d_in[8];
    const float* w_fine = (const float*)d_in[9];
    const float* b_fine = (const float*)d_in[10];
    const float* w_res  = (const float*)d_in[11];
    const float* b_res  = (const float*)d_in[12];
    float* ws  = (float*)d_ws;
    float* out = (float*)d_out;

    // inv denominators staged in d_out (overwritten by k_base afterwards); sm1 zeroes pm+gap
    k_sm1<<<1024, 256, 0, stream>>>(logits, out, ws + OFF_PM);
    k_sm2<<<NBATCH * NP, 256, 0, stream>>>(logits, out, ws + OFF_PM);
    k_base<<<512, 256, 0, stream>>>(feat, ms, w_res, b_fine, b_res, ws + OFF_GAP, out);
    k_small<<<1, 256, 0, stream>>>(ws + OFF_PM, ws + OFF_GAP, sigx, sigy, opac, rho, w_v2,
                                   w_fine, w_res, ws + OFF_K, ws + OFF_ATTN, ws + OFF_WB);
    k_hr<<<768, 256, 0, stream>>>(feat, V, ws + OFF_K, ws + OFF_HR);
    k_conv<<<1024, 256, 0, stream>>>(feat, V, ws + OFF_WB, ws + OFF_HR, ws + OFF_ATTN, out);
}

// Round 11
// 317.032 us; speedup vs baseline: 1.2062x; 1.2062x over previous
//
#include <hip/hip_runtime.h>

#define NBATCH 32
#define NFEAT 48
#define C1c 6
#define LRC 42
#define HH 128
#define WW 128
#define HWSZ 16384
#define NP 81
#define NQ 64

// workspace layout (in floats)
#define OFF_PM   0                      // 81*64 = 5184
#define OFF_GAP  5184                   // 32*42 = 1344  (contiguous after PM -> one memset)
#define OFF_K    6528                   // 64*64 = 4096
#define OFF_ATTN 10624                  // 1344
#define OFF_WB   11968                  // 48*48 = 2304 rearranged weights
#define OFF_HR   14272                  // 32*6*16384 = 3145728

// ---------------- K1a: softmax denominators -> inv (in d_out scratch) + gap sums ----------------
__global__ __launch_bounds__(256) void k_sm1(const float* __restrict__ logits,
                                             const float* __restrict__ feat,
                                             float* __restrict__ invbuf,
                                             float* __restrict__ gap) {
    int idx = blockIdx.x * 256 + threadIdx.x;     // 0..262143 (float2 index)
    int b   = idx >> 13;                          // 8192 float2 per image
    int pos = (idx & 8191) << 1;
    const float* base = logits + (((size_t)b * NP) << 14) + pos;
    float s0 = 0.f, s1 = 0.f;
    for (int p = 0; p < NP; ++p) {
        float2 v = *(const float2*)&base[(size_t)p << 14];
        s0 += __expf(v.x); s1 += __expf(v.y);
    }
    *(float2*)&invbuf[(size_t)idx << 1] = make_float2(1.f / s0, 1.f / s1);
    // gap over feat[b, 6..47] (wave-uniform b)
    int lane = threadIdx.x & 63;
    const float* fb = feat + (((size_t)b * NFEAT + C1c) << 14) + pos;
    for (int c = 0; c < LRC; ++c) {
        float2 f = *(const float2*)&fb[(size_t)c << 14];
        float s = f.x + f.y;
        s += __shfl_xor(s, 1);  s += __shfl_xor(s, 2);  s += __shfl_xor(s, 4);
        s += __shfl_xor(s, 8);  s += __shfl_xor(s, 16); s += __shfl_xor(s, 32);
        if (lane == 0) atomicAdd(&gap[b * LRC + c], s);
    }
}

// ---------------- K1b: binning pass -> pm_sum[81][64] ----------------
__global__ __launch_bounds__(256) void k_sm2(const float* __restrict__ logits,
                                             const float* __restrict__ invbuf,
                                             float* __restrict__ pm_sum) {
    int bid = blockIdx.x;                 // b*81 + p
    int b = bid / NP, p = bid - b * NP;
    const float* base = logits + ((size_t)(b * NP + p) << 14);
    const float* ib   = invbuf + ((size_t)b << 14);
    int tid = threadIdx.x;
    int r0 = tid >> 5, xt = tid & 31;
    float a0 = 0.f, a1 = 0.f, a2 = 0.f, a3 = 0.f;
    int off = (r0 << 7) + (xt << 2);
    for (int k = 0; k < 16; ++k, off += 1024) {
        float4 l4 = *(const float4*)&base[off];
        float4 i4 = *(const float4*)&ib[off];
        a0 += __expf(l4.x) * i4.x;
        a1 += __expf(l4.y) * i4.y;
        a2 += __expf(l4.z) * i4.z;
        a3 += __expf(l4.w) * i4.w;
    }
#pragma unroll
    for (int m = 2; m <= 16; m <<= 1) {
        a0 += __shfl_xor(a0, m); a1 += __shfl_xor(a1, m);
        a2 += __shfl_xor(a2, m); a3 += __shfl_xor(a3, m);
    }
    if (xt < 2) {
        int qb = p * NQ + (r0 << 3) + ((xt & 1) << 2);
        atomicAdd(&pm_sum[qb + 0], a0);
        atomicAdd(&pm_sum[qb + 1], a1);
        atomicAdd(&pm_sum[qb + 2], a2);
        atomicAdd(&pm_sum[qb + 3], a3);
    }
}

// ---------------- K3: build K (64x64), attn (32x42), rearranged weights wbuf[48][48] ----------------
__global__ __launch_bounds__(256) void k_small(const float* __restrict__ pm_sum,
                                               const float* __restrict__ gap_sum,
                                               const float* __restrict__ sigx,
                                               const float* __restrict__ sigy,
                                               const float* __restrict__ opac,
                                               const float* __restrict__ rho,
                                               const float* __restrict__ w_v2,
                                               const float* __restrict__ w_fine,
                                               const float* __restrict__ w_res,
                                               float* __restrict__ Kmat,
                                               float* __restrict__ attn,
                                               float* __restrict__ wbuf) {
    int tid = threadIdx.x;
    if (tid < 64) {
        int q = tid;
        float wsx = 0.f, wsy = 0.f, wop = 0.f, wr = 0.f;
        for (int p = 0; p < NP; ++p) {
            float pv = pm_sum[p * NQ + q] * (1.f / 8192.f);
            wsx += sigx[p] * pv;
            wsy += sigy[p] * pv;
            wop += opac[p] * pv;
            wr  += rho[p]  * pv;
        }
        float a = wsx * wsx, d = wsy * wsy, bc = wr * wsx * wsy;
        float det = a * d - bc * bc;
        float i00 = d / det, i01 = -bc / det, i11 = a / det;
        int iq = q >> 3, jq = q & 7;
        for (int h = 0; h < 8; ++h)
            for (int w = 0; w < 8; ++w) {
                int ki = h - iq + 2, kj = w - jq + 2;
                float val = 0.f;
                if (ki >= 0 && ki < 5 && kj >= 0 && kj < 5) {
                    float xx = -5.f + 2.5f * ki, yy = -5.f + 2.5f * kj;
                    val = wop * __expf(-0.5f * (i00 * xx * xx + 2.f * i01 * xx * yy + i11 * yy * yy));
                }
                Kmat[(q << 6) + (h << 3) + w] = val;
            }
    }
    for (int i = tid; i < NBATCH * LRC; i += 256) {
        int b = i / LRC, co = i % LRC;
        float s = 0.f;
        for (int ci = 0; ci < LRC; ++ci) s += w_v2[co * LRC + ci] * gap_sum[b * LRC + ci];
        s *= (1.f / 16384.f);
        attn[i] = 1.f / (1.f + __expf(-s));
    }
    for (int i = tid; i < NFEAT * 48; i += 256) {
        int c = i / 48, j = i - c * 48;
        float v = 0.f;
        if (j < 36) v = w_fine[(j / 9) * (NFEAT * 9) + c * 9 + (j % 9)];
        else if (j < 40) v = w_res[(j - 36) * NFEAT + c];
        wbuf[i] = v;
    }
}

// ---------------- K4: hr = (colors @ K) * V1 ----------------
__global__ __launch_bounds__(256) void k_hr(const float* __restrict__ feat,
                                            const float* __restrict__ V,
                                            const float* __restrict__ Kmat,
                                            float* __restrict__ hrbuf) {
    __shared__ __align__(16) float lK[4096];          // [q][pos] packed; reads broadcast
    __shared__ __align__(16) float lF[2 * 16 * 128];
    int bid = blockIdx.x;
    int b   = bid / 24;
    int r   = bid - b * 24;
    int strip = r / 3;
    int ch  = (r - strip * 3) * 2;
    int y0  = strip << 4;
    int tid = threadIdx.x;
    {
        const float4* ks = (const float4*)Kmat;
        float4* kd = (float4*)lK;
        for (int i = tid; i < 1024; i += 256) kd[i] = ks[i];
        float4* fd = (float4*)lF;
        const float* fb = feat + (((size_t)b * NFEAT + ch) << 14) + (y0 << 7);
        for (int i = tid; i < 1024; i += 256) {
            int c = i >> 9, rem = i & 511;
            fd[i] = *(const float4*)&fb[((size_t)c << 14) + (rem << 2)];
        }
    }
    __syncthreads();
    int tile = tid >> 3, hrow = tid & 7;
    int tr = tile >> 4, tx = tile & 15;
    float acc[2][8];
#pragma unroll
    for (int c = 0; c < 2; ++c)
#pragma unroll
        for (int j = 0; j < 8; ++j) acc[c][j] = 0.f;
    int fbase = (tr << 3) * 128 + (tx << 3);
    for (int q = 0; q < 64; ++q) {
        int iq = q >> 3, jq = q & 7;
        const float4 k0 = *(const float4*)&lK[(q << 6) + (hrow << 3)];
        const float4 k1 = *(const float4*)&lK[(q << 6) + (hrow << 3) + 4];
#pragma unroll
        for (int c = 0; c < 2; ++c) {
            float col = lF[(c << 11) + fbase + (iq << 7) + jq];
            acc[c][0] += col * k0.x; acc[c][1] += col * k0.y;
            acc[c][2] += col * k0.z; acc[c][3] += col * k0.w;
            acc[c][4] += col * k1.x; acc[c][5] += col * k1.y;
            acc[c][6] += col * k1.z; acc[c][7] += col * k1.w;
        }
    }
    int y = y0 + (tr << 3) + hrow;
#pragma unroll
    for (int c = 0; c < 2; ++c) {
        const float4* vp = (const float4*)(V + (((size_t)b * NFEAT + ch + c) << 14) + ((size_t)y << 7) + (tx << 3));
        float4 v0 = vp[0], v1 = vp[1];
        float4 r0, r1;
        r0.x = acc[c][0] * v0.x; r0.y = acc[c][1] * v0.y; r0.z = acc[c][2] * v0.z; r0.w = acc[c][3] * v0.w;
        r1.x = acc[c][4] * v1.x; r1.y = acc[c][5] * v1.y; r1.z = acc[c][6] * v1.z; r1.w = acc[c][7] * v1.w;
        float4* op = (float4*)(hrbuf + (((size_t)b * C1c + ch + c) << 14) + ((size_t)y << 7) + (tx << 3));
        op[0] = r0; op[1] = r1;
    }
}

// ---------------- K5: fused conv3x3 + conv1x1 + biases + up(ms), 2 wave-groups ----------------
// 16x32 tile, 512 threads. Staging: 1 px/thread over all 8 chans; compute: each group
// (tid>>8) covers 4 chans/interval; LDS merge at end. r9's conflict-free tap map kept.
#define CCH 8
__global__ __launch_bounds__(512, 6) void k_conv(const float* __restrict__ feat,
                                                 const float* __restrict__ V,
                                                 const float* __restrict__ ms,
                                                 const float* __restrict__ wbuf,
                                                 const float* __restrict__ b_fine,
                                                 const float* __restrict__ b_res,
                                                 const float* __restrict__ hrbuf,
                                                 const float* __restrict__ attn,
                                                 float* __restrict__ out) {
    __shared__ float s_in[CCH][18 * 40];   // lds row = input row + 1; lds col = input col + 4
    int bid0 = blockIdx.x;
    int rid  = (bid0 & 7) * 128 + (bid0 >> 3);    // bijective XCD swizzle (1024 = 8*128)
    int b    = rid >> 5;
    int t32  = rid & 31;
    int ty0  = (t32 >> 2) << 4;
    int tx0  = (t32 & 3) << 5;
    int tid  = threadIdx.x;               // 0..511
    int grpu = __builtin_amdgcn_readfirstlane(tid >> 8);   // 0/1, wave-uniform -> scalar
    int ct   = tid & 255;
    int rp   = ct >> 5;                   // 0..7 (row pair)
    int j    = ct & 31;                   // col 0..31
    int gx   = tx0 + j;
    int gy0  = ty0 + 2 * rp;
    int cbase = (2 * rp) * 40 + 3 + j;    // tap base: lds row 2rp = input row 2rp-1

    // staging own pixel (1 px per thread over the 16x32 tile)
    int srow = tid >> 5, scol = tid & 31;
    int sg = ((ty0 + srow) << 7) + tx0 + scol;
    int sl = (srow + 1) * 40 + 4 + scol;

    // halo ring: 100 positions
    bool hhas = tid < 100;
    int rr, cc;
    if (tid < 34)      { rr = 0;        cc = tid; }
    else if (tid < 68) { rr = 17;       cc = tid - 34; }
    else if (tid < 84) { rr = tid - 67; cc = 0; }
    else               { rr = tid - 83; cc = 33; }
    int hsy = ty0 - 1 + rr, hsx = tx0 - 1 + cc;
    float hfm = (hsy >= 0 && hsy < HH && hsx >= 0 && hsx < WW) ? 1.f : 0.f;
    int hoff = (min(HH - 1, max(0, hsy)) << 7) + min(WW - 1, max(0, hsx));
    int hlds = rr * 40 + 3 + cc;

    const float* atb = attn + b * LRC;
    float a0[4] = {0.f, 0.f, 0.f, 0.f};   // conv partial, row gy0
    float a1[4] = {0.f, 0.f, 0.f, 0.f};   // conv partial, row gy0+1
    float x1[4] = {0.f, 0.f, 0.f, 0.f};   // 1x1 full sum for staging px

    for (int cb = 0; cb < NFEAT; cb += CCH) {
        __syncthreads();
        // ---- stage 8 channels, 1 px each + halo; fold 1x1 on the way ----
        for (int k = 0; k < CCH; ++k) {
            int c = cb + k;
            const float* wb = wbuf + c * 48;                  // uniform -> s_load
            float wr0 = wb[36], wr1 = wb[37], wr2 = wb[38], wr3 = wb[39];
            float fown;
            if (c < C1c) {
                const float* hsrc = hrbuf + (((size_t)b * C1c + c) << 14);
                const float* fsrc = feat  + (((size_t)b * NFEAT + c) << 14);
                s_in[k][sl] = hsrc[sg];
                fown = fsrc[sg];
                if (hhas) s_in[k][hlds] = hsrc[hoff] * hfm;
            } else {
                float am = atb[c - C1c];
                const float* fsrc = feat + (((size_t)b * NFEAT + c) << 14);
                const float* vsrc = V    + (((size_t)b * NFEAT + c) << 14);
                fown = fsrc[sg];
                s_in[k][sl] = fown * vsrc[sg] * am;
                if (hhas) s_in[k][hlds] = fsrc[hoff] * vsrc[hoff] * (am * hfm);
            }
            x1[0] += wr0 * fown; x1[1] += wr1 * fown;
            x1[2] += wr2 * fown; x1[3] += wr3 * fown;
        }
        __syncthreads();
        // ---- compute: this group's 4 channels ----
        for (int k = 0; k < 4; ++k) {
            int slot = 4 * grpu + k;
            int c = cb + slot;
            const float* wc = wbuf + c * 48;                  // scalar -> s_load
            float t00 = s_in[slot][cbase],       t01 = s_in[slot][cbase + 1],   t02 = s_in[slot][cbase + 2];
            float t10 = s_in[slot][cbase + 40],  t11 = s_in[slot][cbase + 41],  t12 = s_in[slot][cbase + 42];
            float t20 = s_in[slot][cbase + 80],  t21 = s_in[slot][cbase + 81],  t22 = s_in[slot][cbase + 82];
            float t30 = s_in[slot][cbase + 120], t31 = s_in[slot][cbase + 121], t32 = s_in[slot][cbase + 122];
#pragma unroll
            for (int o = 0; o < 4; ++o) {
                float w0 = wc[o * 9 + 0], w1 = wc[o * 9 + 1], w2 = wc[o * 9 + 2];
                float w3 = wc[o * 9 + 3], w4 = wc[o * 9 + 4], w5 = wc[o * 9 + 5];
                float w6 = wc[o * 9 + 6], w7 = wc[o * 9 + 7], w8 = wc[o * 9 + 8];
                a0[o] += w0 * t00 + w1 * t01 + w2 * t02
                       + w3 * t10 + w4 * t11 + w5 * t12
                       + w6 * t20 + w7 * t21 + w8 * t22;
                a1[o] += w0 * t10 + w1 * t11 + w2 * t12
                       + w3 * t20 + w4 * t21 + w5 * t22
                       + w6 * t30 + w7 * t31 + w8 * t32;
            }
        }
    }
    // ---- merge: group1 conv partials -> group0; x1 redistribute; epilogue ----
    __syncthreads();
    int p0 = (2 * rp) * 32 + j, p1 = p0 + 32;    // tile-local px indices
    float* sm = &s_in[0][0];                     // reuse LDS (needs 2048 floats)
    if (grpu == 1) {
#pragma unroll
        for (int o = 0; o < 4; ++o) { sm[o * 512 + p0] = a0[o]; sm[o * 512 + p1] = a1[o]; }
    }
    __syncthreads();
    if (grpu == 0) {
#pragma unroll
        for (int o = 0; o < 4; ++o) { a0[o] += sm[o * 512 + p0]; a1[o] += sm[o * 512 + p1]; }
    }
    __syncthreads();
#pragma unroll
    for (int o = 0; o < 4; ++o) sm[o * 512 + tid] = x1[o];   // staging px == tid
    __syncthreads();
    if (grpu == 0) {
        float sxf = (gx + 0.5f) * 0.25f - 0.5f;
        int x0i = (int)floorf(sxf); float fx = sxf - (float)x0i;
        int x0c = min(31, max(0, x0i)), x1c = min(31, max(0, x0i + 1));
        float syf0 = (gy0 + 0.5f) * 0.25f - 0.5f;
        int y0i = (int)floorf(syf0); float fy0 = syf0 - (float)y0i;
        int y0c0 = min(31, max(0, y0i)), y1c0 = min(31, max(0, y0i + 1));
        float syf1 = (gy0 + 1.5f) * 0.25f - 0.5f;
        int y1i = (int)floorf(syf1); float fy1 = syf1 - (float)y1i;
        int y0c1 = min(31, max(0, y1i)), y1c1 = min(31, max(0, y1i + 1));
#pragma unroll
        for (int o = 0; o < 4; ++o) {
            const float* mb = ms + ((size_t)(b * 4 + o) << 10);
            float addc = b_fine[o] + b_res[o];
            float m00 = mb[(y0c0 << 5) + x0c], m01 = mb[(y0c0 << 5) + x1c];
            float m10 = mb[(y1c0 << 5) + x0c], m11 = mb[(y1c0 << 5) + x1c];
            float up0 = (m00 * (1.f - fx) + m01 * fx) * (1.f - fy0)
                      + (m10 * (1.f - fx) + m11 * fx) * fy0;
            float n00 = mb[(y0c1 << 5) + x0c], n01 = mb[(y0c1 << 5) + x1c];
            float n10 = mb[(y1c1 << 5) + x0c], n11 = mb[(y1c1 << 5) + x1c];
            float up1 = (n00 * (1.f - fx) + n01 * fx) * (1.f - fy1)
                      + (n10 * (1.f - fx) + n11 * fx) * fy1;
            size_t obase = ((size_t)(b * 4 + o)) << 14;
            out[obase + (gy0 << 7) + gx]       = a0[o] + sm[o * 512 + p0] + addc + up0;
            out[obase + ((gy0 + 1) << 7) + gx] = a1[o] + sm[o * 512 + p1] + addc + up1;
        }
    }
}

extern "C" void kernel_launch(void* const* d_in, const int* in_sizes, int n_in,
                              void* d_out, int out_size, void* d_ws, size_t ws_size,
                              hipStream_t stream) {
    (void)in_sizes; (void)n_in; (void)out_size; (void)ws_size;
    const float* ms     = (const float*)d_in[0];
    const float* feat   = (const float*)d_in[1];
    const float* V      = (const float*)d_in[2];
    const float* logits = (const float*)d_in[3];
    const float* sigx   = (const float*)d_in[4];
    const float* sigy   = (const float*)d_in[5];
    const float* opac   = (const float*)d_in[6];
    const float* rho    = (const float*)d_in[7];
    const float* w_v2   = (const float*)d_in[8];
    const float* w_fine = (const float*)d_in[9];
    const float* b_fine = (const float*)d_in[10];
    const float* w_res  = (const float*)d_in[11];
    const float* b_res  = (const float*)d_in[12];
    float* ws  = (float*)d_ws;
    float* out = (float*)d_out;

    // zero pm_sum + gap (atomically accumulated by sm2 / sm1)
    hipMemsetAsync(ws + OFF_PM, 0, (size_t)(NP * NQ + NBATCH * LRC) * sizeof(float), stream);
    // inv denominators staged in d_out (consumed by sm2, then overwritten by conv)
    k_sm1<<<1024, 256, 0, stream>>>(logits, feat, out, ws + OFF_GAP);
    k_sm2<<<NBATCH * NP, 256, 0, stream>>>(logits, out, ws + OFF_PM);
    k_small<<<1, 256, 0, stream>>>(ws + OFF_PM, ws + OFF_GAP, sigx, sigy, opac, rho, w_v2,
                                   w_fine, w_res, ws + OFF_K, ws + OFF_ATTN, ws + OFF_WB);
    k_hr<<<768, 256, 0, stream>>>(feat, V, ws + OFF_K, ws + OFF_HR);
    k_conv<<<1024, 512, 0, stream>>>(feat, V, ms, ws + OFF_WB, b_fine, b_res,
                                     ws + OFF_HR, ws + OFF_ATTN, out);
}

// Round 12
// 260.020 us; speedup vs baseline: 1.4706x; 1.2193x over previous
//
#include <hip/hip_runtime.h>

#define NBATCH 32
#define NFEAT 48
#define C1c 6
#define LRC 42
#define HH 128
#define WW 128
#define HWSZ 16384
#define NP 81
#define NQ 64

// workspace layout (in floats)
#define OFF_PM   0                      // 81*64 = 5184
#define OFF_GAP  5184                   // 32*42 = 1344  (contiguous after PM -> one memset)
#define OFF_K    6528                   // 64*64 = 4096
#define OFF_ATTN 10624                  // 1344
#define OFF_WB   11968                  // 48*48 = 2304 rearranged weights
#define OFF_HR   14272                  // 32*6*16384 = 3145728
// inv denominators (524288 floats) reuse the OFF_HR region: consumed by k_sm2 BEFORE k_hr writes.

// ---------------- Phase 1 (heterogeneous): A) softmax denominators  B) gap + 1x1 base + up(ms) ----
__global__ __launch_bounds__(256) void k_phase1(const float* __restrict__ logits,
                                                const float* __restrict__ feat,
                                                const float* __restrict__ ms,
                                                const float* __restrict__ w_res,
                                                const float* __restrict__ b_fine,
                                                const float* __restrict__ b_res,
                                                float* __restrict__ invbuf,
                                                float* __restrict__ gap,
                                                float* __restrict__ out) {
    int bid = blockIdx.x;
    int tid = threadIdx.x;
    if (bid < 1024) {
        // ---- A: per-pixel softmax denominator -> inv (float2/thread) ----
        int idx = bid * 256 + tid;                    // 0..262143 (float2 index)
        int b   = idx >> 13;                          // 8192 float2 per image
        int pos = (idx & 8191) << 1;
        const float* base = logits + (((size_t)b * NP) << 14) + pos;
        float s0 = 0.f, s1 = 0.f;
        for (int p = 0; p < NP; ++p) {
            float2 v = *(const float2*)&base[(size_t)p << 14];
            s0 += __expf(v.x); s1 += __expf(v.y);
        }
        *(float2*)&invbuf[(size_t)idx << 1] = make_float2(1.f / s0, 1.f / s1);
    } else {
        // ---- B: gap sums + 1x1 base + biases + up(ms) -> out (4 px/thread) ----
        int gid = bid - 1024;                         // 0..511
        int b = gid >> 4, strip = gid & 15;
        int row = (strip << 3) + (tid >> 5);
        int x0  = (tid & 31) << 2;
        int poff = (row << 7) + x0;
        int lane = tid & 63;
        const float* fb = feat + (((size_t)b * NFEAT) << 14);
        float a[4][4];
#pragma unroll
        for (int j = 0; j < 4; ++j)
#pragma unroll
            for (int o = 0; o < 4; ++o) a[j][o] = 0.f;
        for (int c = 0; c < NFEAT; ++c) {
            float4 f = *(const float4*)&fb[((size_t)c << 14) + poff];
            float wr0 = w_res[c], wr1 = w_res[NFEAT + c];
            float wr2 = w_res[2 * NFEAT + c], wr3 = w_res[3 * NFEAT + c];
            a[0][0] += wr0 * f.x; a[0][1] += wr1 * f.x; a[0][2] += wr2 * f.x; a[0][3] += wr3 * f.x;
            a[1][0] += wr0 * f.y; a[1][1] += wr1 * f.y; a[1][2] += wr2 * f.y; a[1][3] += wr3 * f.y;
            a[2][0] += wr0 * f.z; a[2][1] += wr1 * f.z; a[2][2] += wr2 * f.z; a[2][3] += wr3 * f.z;
            a[3][0] += wr0 * f.w; a[3][1] += wr1 * f.w; a[3][2] += wr2 * f.w; a[3][3] += wr3 * f.w;
            if (c >= C1c) {
                float s = (f.x + f.y) + (f.z + f.w);
                s += __shfl_xor(s, 1);  s += __shfl_xor(s, 2);  s += __shfl_xor(s, 4);
                s += __shfl_xor(s, 8);  s += __shfl_xor(s, 16); s += __shfl_xor(s, 32);
                if (lane == 0) atomicAdd(&gap[b * LRC + (c - C1c)], s);
            }
        }
        float syf = (row + 0.5f) * 0.25f - 0.5f;
        int y0i = (int)floorf(syf); float fy = syf - (float)y0i;
        int y0c = min(31, max(0, y0i)), y1c = min(31, max(0, y0i + 1));
        float fxv[4]; int x0v[4], x1v[4];
#pragma unroll
        for (int j = 0; j < 4; ++j) {
            float sxf = (x0 + j + 0.5f) * 0.25f - 0.5f;
            int x0i = (int)floorf(sxf);
            fxv[j] = sxf - (float)x0i;
            x0v[j] = min(31, max(0, x0i));
            x1v[j] = min(31, max(0, x0i + 1));
        }
#pragma unroll
        for (int o = 0; o < 4; ++o) {
            const float* mb = ms + ((size_t)(b * 4 + o) << 10);
            float addc = b_fine[o] + b_res[o];
            float res[4];
#pragma unroll
            for (int j = 0; j < 4; ++j) {
                float m00 = mb[(y0c << 5) + x0v[j]], m01 = mb[(y0c << 5) + x1v[j]];
                float m10 = mb[(y1c << 5) + x0v[j]], m11 = mb[(y1c << 5) + x1v[j]];
                float up = (m00 * (1.f - fxv[j]) + m01 * fxv[j]) * (1.f - fy)
                         + (m10 * (1.f - fxv[j]) + m11 * fxv[j]) * fy;
                res[j] = a[j][o] + addc + up;
            }
            *(float4*)&out[(((size_t)(b * 4 + o)) << 14) + poff] =
                make_float4(res[0], res[1], res[2], res[3]);
        }
    }
}

// ---------------- K1b: binning pass -> pm_sum[81][64] ----------------
__global__ __launch_bounds__(256) void k_sm2(const float* __restrict__ logits,
                                             const float* __restrict__ invbuf,
                                             float* __restrict__ pm_sum) {
    int bid = blockIdx.x;                 // b*81 + p
    int b = bid / NP, p = bid - b * NP;
    const float* base = logits + ((size_t)(b * NP + p) << 14);
    const float* ib   = invbuf + ((size_t)b << 14);
    int tid = threadIdx.x;
    int r0 = tid >> 5, xt = tid & 31;
    float a0 = 0.f, a1 = 0.f, a2 = 0.f, a3 = 0.f;
    int off = (r0 << 7) + (xt << 2);
    for (int k = 0; k < 16; ++k, off += 1024) {
        float4 l4 = *(const float4*)&base[off];
        float4 i4 = *(const float4*)&ib[off];
        a0 += __expf(l4.x) * i4.x;
        a1 += __expf(l4.y) * i4.y;
        a2 += __expf(l4.z) * i4.z;
        a3 += __expf(l4.w) * i4.w;
    }
#pragma unroll
    for (int m = 2; m <= 16; m <<= 1) {
        a0 += __shfl_xor(a0, m); a1 += __shfl_xor(a1, m);
        a2 += __shfl_xor(a2, m); a3 += __shfl_xor(a3, m);
    }
    if (xt < 2) {
        int qb = p * NQ + (r0 << 3) + ((xt & 1) << 2);
        atomicAdd(&pm_sum[qb + 0], a0);
        atomicAdd(&pm_sum[qb + 1], a1);
        atomicAdd(&pm_sum[qb + 2], a2);
        atomicAdd(&pm_sum[qb + 3], a3);
    }
}

// ---------------- K3: build K (64x64), attn (32x42), rearranged weights wbuf[48][48] ----------------
__global__ __launch_bounds__(256) void k_small(const float* __restrict__ pm_sum,
                                               const float* __restrict__ gap_sum,
                                               const float* __restrict__ sigx,
                                               const float* __restrict__ sigy,
                                               const float* __restrict__ opac,
                                               const float* __restrict__ rho,
                                               const float* __restrict__ w_v2,
                                               const float* __restrict__ w_fine,
                                               const float* __restrict__ w_res,
                                               float* __restrict__ Kmat,
                                               float* __restrict__ attn,
                                               float* __restrict__ wbuf) {
    int tid = threadIdx.x;
    if (tid < 64) {
        int q = tid;
        float wsx = 0.f, wsy = 0.f, wop = 0.f, wr = 0.f;
        for (int p = 0; p < NP; ++p) {
            float pv = pm_sum[p * NQ + q] * (1.f / 8192.f);
            wsx += sigx[p] * pv;
            wsy += sigy[p] * pv;
            wop += opac[p] * pv;
            wr  += rho[p]  * pv;
        }
        float a = wsx * wsx, d = wsy * wsy, bc = wr * wsx * wsy;
        float det = a * d - bc * bc;
        float i00 = d / det, i01 = -bc / det, i11 = a / det;
        int iq = q >> 3, jq = q & 7;
        for (int h = 0; h < 8; ++h)
            for (int w = 0; w < 8; ++w) {
                int ki = h - iq + 2, kj = w - jq + 2;
                float val = 0.f;
                if (ki >= 0 && ki < 5 && kj >= 0 && kj < 5) {
                    float xx = -5.f + 2.5f * ki, yy = -5.f + 2.5f * kj;
                    val = wop * __expf(-0.5f * (i00 * xx * xx + 2.f * i01 * xx * yy + i11 * yy * yy));
                }
                Kmat[(q << 6) + (h << 3) + w] = val;
            }
    }
    for (int i = tid; i < NBATCH * LRC; i += 256) {
        int b = i / LRC, co = i % LRC;
        float s = 0.f;
        for (int ci = 0; ci < LRC; ++ci) s += w_v2[co * LRC + ci] * gap_sum[b * LRC + ci];
        s *= (1.f / 16384.f);
        attn[i] = 1.f / (1.f + __expf(-s));
    }
    for (int i = tid; i < NFEAT * 48; i += 256) {
        int c = i / 48, j = i - c * 48;
        float v = 0.f;
        if (j < 36) v = w_fine[(j / 9) * (NFEAT * 9) + c * 9 + (j % 9)];
        else if (j < 40) v = w_res[(j - 36) * NFEAT + c];
        wbuf[i] = v;
    }
}

// ---------------- K4: hr = (colors @ K) * V1 ----------------
__global__ __launch_bounds__(256) void k_hr(const float* __restrict__ feat,
                                            const float* __restrict__ V,
                                            const float* __restrict__ Kmat,
                                            float* __restrict__ hrbuf) {
    __shared__ __align__(16) float lK[4096];          // [q][pos] packed; reads broadcast
    __shared__ __align__(16) float lF[2 * 16 * 128];
    int bid = blockIdx.x;
    int b   = bid / 24;
    int r   = bid - b * 24;
    int strip = r / 3;
    int ch  = (r - strip * 3) * 2;
    int y0  = strip << 4;
    int tid = threadIdx.x;
    {
        const float4* ks = (const float4*)Kmat;
        float4* kd = (float4*)lK;
        for (int i = tid; i < 1024; i += 256) kd[i] = ks[i];
        float4* fd = (float4*)lF;
        const float* fb = feat + (((size_t)b * NFEAT + ch) << 14) + (y0 << 7);
        for (int i = tid; i < 1024; i += 256) {
            int c = i >> 9, rem = i & 511;
            fd[i] = *(const float4*)&fb[((size_t)c << 14) + (rem << 2)];
        }
    }
    __syncthreads();
    int tile = tid >> 3, hrow = tid & 7;
    int tr = tile >> 4, tx = tile & 15;
    float acc[2][8];
#pragma unroll
    for (int c = 0; c < 2; ++c)
#pragma unroll
        for (int j = 0; j < 8; ++j) acc[c][j] = 0.f;
    int fbase = (tr << 3) * 128 + (tx << 3);
    for (int q = 0; q < 64; ++q) {
        int iq = q >> 3, jq = q & 7;
        const float4 k0 = *(const float4*)&lK[(q << 6) + (hrow << 3)];
        const float4 k1 = *(const float4*)&lK[(q << 6) + (hrow << 3) + 4];
#pragma unroll
        for (int c = 0; c < 2; ++c) {
            float col = lF[(c << 11) + fbase + (iq << 7) + jq];
            acc[c][0] += col * k0.x; acc[c][1] += col * k0.y;
            acc[c][2] += col * k0.z; acc[c][3] += col * k0.w;
            acc[c][4] += col * k1.x; acc[c][5] += col * k1.y;
            acc[c][6] += col * k1.z; acc[c][7] += col * k1.w;
        }
    }
    int y = y0 + (tr << 3) + hrow;
#pragma unroll
    for (int c = 0; c < 2; ++c) {
        const float4* vp = (const float4*)(V + (((size_t)b * NFEAT + ch + c) << 14) + ((size_t)y << 7) + (tx << 3));
        float4 v0 = vp[0], v1 = vp[1];
        float4 r0, r1;
        r0.x = acc[c][0] * v0.x; r0.y = acc[c][1] * v0.y; r0.z = acc[c][2] * v0.z; r0.w = acc[c][3] * v0.w;
        r1.x = acc[c][4] * v1.x; r1.y = acc[c][5] * v1.y; r1.z = acc[c][6] * v1.z; r1.w = acc[c][7] * v1.w;
        float4* op = (float4*)(hrbuf + (((size_t)b * C1c + ch + c) << 14) + ((size_t)y << 7) + (tx << 3));
        op[0] = r0; op[1] = r1;
    }
}

// ---------------- K5: conv3x3 (RMW onto base), 2 wave-groups, no spill config ----------------
// 16x32 tile, 512 threads, launch_bounds(512,4) -> 128 VGPR cap (r9-proven headroom).
// Staging: 1 px/thread over 8 chans; compute: 4 chans/group; LDS merge; RMW out.
#define CCH 8
__global__ __launch_bounds__(512, 4) void k_conv(const float* __restrict__ feat,
                                                 const float* __restrict__ V,
                                                 const float* __restrict__ wbuf,
                                                 const float* __restrict__ hrbuf,
                                                 const float* __restrict__ attn,
                                                 float* __restrict__ out) {
    __shared__ float s_in[CCH][18 * 40];   // lds row = input row + 1; lds col = input col + 4
    int bid0 = blockIdx.x;
    int rid  = (bid0 & 7) * 128 + (bid0 >> 3);    // bijective XCD swizzle (1024 = 8*128)
    int b    = rid >> 5;
    int t32  = rid & 31;
    int ty0  = (t32 >> 2) << 4;
    int tx0  = (t32 & 3) << 5;
    int tid  = threadIdx.x;               // 0..511
    int grpu = __builtin_amdgcn_readfirstlane(tid >> 8);   // 0/1, wave-uniform -> scalar
    int ct   = tid & 255;
    int rp   = ct >> 5;                   // 0..7 (row pair)
    int j    = ct & 31;                   // col 0..31
    int gx   = tx0 + j;
    int gy0  = ty0 + 2 * rp;
    int cbase = (2 * rp) * 40 + 3 + j;    // tap base: lds row 2rp = input row 2rp-1

    // staging own pixel (1 px per thread over the 16x32 tile)
    int srow = tid >> 5, scol = tid & 31;
    int sg = ((ty0 + srow) << 7) + tx0 + scol;
    int sl = (srow + 1) * 40 + 4 + scol;

    // halo ring: 100 positions
    bool hhas = tid < 100;
    int rr, cc;
    if (tid < 34)      { rr = 0;        cc = tid; }
    else if (tid < 68) { rr = 17;       cc = tid - 34; }
    else if (tid < 84) { rr = tid - 67; cc = 0; }
    else               { rr = tid - 83; cc = 33; }
    int hsy = ty0 - 1 + rr, hsx = tx0 - 1 + cc;
    float hfm = (hsy >= 0 && hsy < HH && hsx >= 0 && hsx < WW) ? 1.f : 0.f;
    int hoff = (min(HH - 1, max(0, hsy)) << 7) + min(WW - 1, max(0, hsx));
    int hlds = rr * 40 + 3 + cc;

    const float* atb = attn + b * LRC;
    float a0[4] = {0.f, 0.f, 0.f, 0.f};   // conv partial, row gy0
    float a1[4] = {0.f, 0.f, 0.f, 0.f};   // conv partial, row gy0+1

    for (int cb = 0; cb < NFEAT; cb += CCH) {
        __syncthreads();
        // ---- stage 8 channels, 1 px each + halo ----
        for (int k = 0; k < CCH; ++k) {
            int c = cb + k;
            if (c < C1c) {
                const float* hsrc = hrbuf + (((size_t)b * C1c + c) << 14);
                s_in[k][sl] = hsrc[sg];
                if (hhas) s_in[k][hlds] = hsrc[hoff] * hfm;
            } else {
                float am = atb[c - C1c];
                const float* fsrc = feat + (((size_t)b * NFEAT + c) << 14);
                const float* vsrc = V    + (((size_t)b * NFEAT + c) << 14);
                s_in[k][sl] = fsrc[sg] * vsrc[sg] * am;
                if (hhas) s_in[k][hlds] = fsrc[hoff] * vsrc[hoff] * (am * hfm);
            }
        }
        __syncthreads();
        // ---- compute: this group's 4 channels ----
        for (int k = 0; k < 4; ++k) {
            int slot = 4 * grpu + k;
            int c = cb + slot;
            const float* wc = wbuf + c * 48;                  // scalar -> s_load
            float t00 = s_in[slot][cbase],       t01 = s_in[slot][cbase + 1],   t02 = s_in[slot][cbase + 2];
            float t10 = s_in[slot][cbase + 40],  t11 = s_in[slot][cbase + 41],  t12 = s_in[slot][cbase + 42];
            float t20 = s_in[slot][cbase + 80],  t21 = s_in[slot][cbase + 81],  t22 = s_in[slot][cbase + 82];
            float t30 = s_in[slot][cbase + 120], t31 = s_in[slot][cbase + 121], t32 = s_in[slot][cbase + 122];
#pragma unroll
            for (int o = 0; o < 4; ++o) {
                float w0 = wc[o * 9 + 0], w1 = wc[o * 9 + 1], w2 = wc[o * 9 + 2];
                float w3 = wc[o * 9 + 3], w4 = wc[o * 9 + 4], w5 = wc[o * 9 + 5];
                float w6 = wc[o * 9 + 6], w7 = wc[o * 9 + 7], w8 = wc[o * 9 + 8];
                a0[o] += w0 * t00 + w1 * t01 + w2 * t02
                       + w3 * t10 + w4 * t11 + w5 * t12
                       + w6 * t20 + w7 * t21 + w8 * t22;
                a1[o] += w0 * t10 + w1 * t11 + w2 * t12
                       + w3 * t20 + w4 * t21 + w5 * t22
                       + w6 * t30 + w7 * t31 + w8 * t32;
            }
        }
    }
    // ---- merge group1 -> group0, then RMW stores (group0 only) ----
    __syncthreads();
    float* sm = &s_in[0][0];                     // reuse LDS (2048 floats needed)
    int p0 = (2 * rp) * 32 + j, p1 = p0 + 32;
    if (grpu == 1) {
#pragma unroll
        for (int o = 0; o < 4; ++o) { sm[o * 512 + p0] = a0[o]; sm[o * 512 + p1] = a1[o]; }
    }
    __syncthreads();
    if (grpu == 0) {
#pragma unroll
        for (int o = 0; o < 4; ++o) {
            size_t obase = ((size_t)(b * 4 + o)) << 14;
            float* op0 = out + obase + (gy0 << 7) + gx;
            float* op1 = out + obase + ((gy0 + 1) << 7) + gx;
            *op0 = *op0 + a0[o] + sm[o * 512 + p0];
            *op1 = *op1 + a1[o] + sm[o * 512 + p1];
        }
    }
}

extern "C" void kernel_launch(void* const* d_in, const int* in_sizes, int n_in,
                              void* d_out, int out_size, void* d_ws, size_t ws_size,
                              hipStream_t stream) {
    (void)in_sizes; (void)n_in; (void)out_size; (void)ws_size;
    const float* ms     = (const float*)d_in[0];
    const float* feat   = (const float*)d_in[1];
    const float* V      = (const float*)d_in[2];
    const float* logits = (const float*)d_in[3];
    const float* sigx   = (const float*)d_in[4];
    const float* sigy   = (const float*)d_in[5];
    const float* opac   = (const float*)d_in[6];
    const float* rho    = (const float*)d_in[7];
    const float* w_v2   = (const float*)d_in[8];
    const float* w_fine = (const float*)d_in[9];
    const float* b_fine = (const float*)d_in[10];
    const float* w_res  = (const float*)d_in[11];
    const float* b_res  = (const float*)d_in[12];
    float* ws  = (float*)d_ws;
    float* out = (float*)d_out;
    float* inv = ws + OFF_HR;   // disjoint lifetime with hrbuf (consumed by sm2 before k_hr)

    // zero pm_sum + gap
    hipMemsetAsync(ws + OFF_PM, 0, (size_t)(NP * NQ + NBATCH * LRC) * sizeof(float), stream);
    k_phase1<<<1024 + 512, 256, 0, stream>>>(logits, feat, ms, w_res, b_fine, b_res,
                                             inv, ws + OFF_GAP, out);
    k_sm2<<<NBATCH * NP, 256, 0, stream>>>(logits, inv, ws + OFF_PM);
    k_small<<<1, 256, 0, stream>>>(ws + OFF_PM, ws + OFF_GAP, sigx, sigy, opac, rho, w_v2,
                                   w_fine, w_res, ws + OFF_K, ws + OFF_ATTN, ws + OFF_WB);
    k_hr<<<768, 256, 0, stream>>>(feat, V, ws + OFF_K, ws + OFF_HR);
    k_conv<<<1024, 512, 0, stream>>>(feat, V, ws + OFF_WB, ws + OFF_HR, ws + OFF_ATTN, out);
}

// Round 13
// 245.068 us; speedup vs baseline: 1.5603x; 1.0610x over previous
//
#include <hip/hip_runtime.h>

#define NBATCH 32
#define NFEAT 48
#define C1c 6
#define LRC 42
#define HH 128
#define WW 128
#define HWSZ 16384
#define NP 81
#define NQ 64

// workspace layout (in floats)
#define OFF_PM   0                      // 81*64 = 5184
#define OFF_GAP  5184                   // 32*42 = 1344  (contiguous after PM -> one memset)
#define OFF_K    6528                   // 64*64 = 4096
#define OFF_ATTN 10624                  // 1344
#define OFF_WB   11968                  // 48*48 = 2304 rearranged weights
#define OFF_HR   14272                  // 32*6*16384 = 3145728
// inv denominators (524288 floats) reuse the OFF_HR region: consumed by k_sm2 BEFORE k_hr writes.

// ---------------- Phase 1 (heterogeneous): A) softmax denominators  B) gap + 1x1 base + up(ms) ----
__global__ __launch_bounds__(256) void k_phase1(const float* __restrict__ logits,
                                                const float* __restrict__ feat,
                                                const float* __restrict__ ms,
                                                const float* __restrict__ w_res,
                                                const float* __restrict__ b_fine,
                                                const float* __restrict__ b_res,
                                                float* __restrict__ invbuf,
                                                float* __restrict__ gap,
                                                float* __restrict__ out) {
    int bid = blockIdx.x;
    int tid = threadIdx.x;
    if (bid < 512) {
        // ---- A: per-pixel softmax denominator -> inv (float4/thread, deep load pipeline) ----
        int idx = bid * 256 + tid;                    // 0..131071 (float4 index)
        int b   = idx >> 12;                          // 4096 float4 per image
        int pos = (idx & 4095) << 2;
        const float* base = logits + (((size_t)b * NP) << 14) + pos;
        float s0 = 0.f, s1 = 0.f, s2 = 0.f, s3 = 0.f;
#pragma unroll 9
        for (int p = 0; p < NP; ++p) {
            float4 v = *(const float4*)&base[(size_t)p << 14];
            s0 += __expf(v.x); s1 += __expf(v.y); s2 += __expf(v.z); s3 += __expf(v.w);
        }
        *(float4*)&invbuf[(size_t)idx << 2] =
            make_float4(1.f / s0, 1.f / s1, 1.f / s2, 1.f / s3);
    } else {
        // ---- B: gap sums + 1x1 base + biases + up(ms) -> out (4 px/thread) ----
        int gid = bid - 512;                          // 0..511
        int b = gid >> 4, strip = gid & 15;
        int row = (strip << 3) + (tid >> 5);
        int x0  = (tid & 31) << 2;
        int poff = (row << 7) + x0;
        int lane = tid & 63;
        const float* fb = feat + (((size_t)b * NFEAT) << 14);
        float a[4][4];
#pragma unroll
        for (int j = 0; j < 4; ++j)
#pragma unroll
            for (int o = 0; o < 4; ++o) a[j][o] = 0.f;
        for (int c = 0; c < NFEAT; ++c) {
            float4 f = *(const float4*)&fb[((size_t)c << 14) + poff];
            float wr0 = w_res[c], wr1 = w_res[NFEAT + c];
            float wr2 = w_res[2 * NFEAT + c], wr3 = w_res[3 * NFEAT + c];
            a[0][0] += wr0 * f.x; a[0][1] += wr1 * f.x; a[0][2] += wr2 * f.x; a[0][3] += wr3 * f.x;
            a[1][0] += wr0 * f.y; a[1][1] += wr1 * f.y; a[1][2] += wr2 * f.y; a[1][3] += wr3 * f.y;
            a[2][0] += wr0 * f.z; a[2][1] += wr1 * f.z; a[2][2] += wr2 * f.z; a[2][3] += wr3 * f.z;
            a[3][0] += wr0 * f.w; a[3][1] += wr1 * f.w; a[3][2] += wr2 * f.w; a[3][3] += wr3 * f.w;
            if (c >= C1c) {
                float s = (f.x + f.y) + (f.z + f.w);
                s += __shfl_xor(s, 1);  s += __shfl_xor(s, 2);  s += __shfl_xor(s, 4);
                s += __shfl_xor(s, 8);  s += __shfl_xor(s, 16); s += __shfl_xor(s, 32);
                if (lane == 0) atomicAdd(&gap[b * LRC + (c - C1c)], s);
            }
        }
        float syf = (row + 0.5f) * 0.25f - 0.5f;
        int y0i = (int)floorf(syf); float fy = syf - (float)y0i;
        int y0c = min(31, max(0, y0i)), y1c = min(31, max(0, y0i + 1));
        float fxv[4]; int x0v[4], x1v[4];
#pragma unroll
        for (int j = 0; j < 4; ++j) {
            float sxf = (x0 + j + 0.5f) * 0.25f - 0.5f;
            int x0i = (int)floorf(sxf);
            fxv[j] = sxf - (float)x0i;
            x0v[j] = min(31, max(0, x0i));
            x1v[j] = min(31, max(0, x0i + 1));
        }
#pragma unroll
        for (int o = 0; o < 4; ++o) {
            const float* mb = ms + ((size_t)(b * 4 + o) << 10);
            float addc = b_fine[o] + b_res[o];
            float res[4];
#pragma unroll
            for (int j = 0; j < 4; ++j) {
                float m00 = mb[(y0c << 5) + x0v[j]], m01 = mb[(y0c << 5) + x1v[j]];
                float m10 = mb[(y1c << 5) + x0v[j]], m11 = mb[(y1c << 5) + x1v[j]];
                float up = (m00 * (1.f - fxv[j]) + m01 * fxv[j]) * (1.f - fy)
                         + (m10 * (1.f - fxv[j]) + m11 * fxv[j]) * fy;
                res[j] = a[j][o] + addc + up;
            }
            *(float4*)&out[(((size_t)(b * 4 + o)) << 14) + poff] =
                make_float4(res[0], res[1], res[2], res[3]);
        }
    }
}

// ---------------- K1b: binning pass -> pm_sum[81][64] ----------------
__global__ __launch_bounds__(256) void k_sm2(const float* __restrict__ logits,
                                             const float* __restrict__ invbuf,
                                             float* __restrict__ pm_sum) {
    int bid = blockIdx.x;                 // b*81 + p
    int b = bid / NP, p = bid - b * NP;
    const float* base = logits + ((size_t)(b * NP + p) << 14);
    const float* ib   = invbuf + ((size_t)b << 14);
    int tid = threadIdx.x;
    int r0 = tid >> 5, xt = tid & 31;
    float a0 = 0.f, a1 = 0.f, a2 = 0.f, a3 = 0.f;
    int off = (r0 << 7) + (xt << 2);
#pragma unroll 4
    for (int k = 0; k < 16; ++k) {
        int o2 = off + k * 1024;
        float4 l4 = *(const float4*)&base[o2];
        float4 i4 = *(const float4*)&ib[o2];
        a0 += __expf(l4.x) * i4.x;
        a1 += __expf(l4.y) * i4.y;
        a2 += __expf(l4.z) * i4.z;
        a3 += __expf(l4.w) * i4.w;
    }
#pragma unroll
    for (int m = 2; m <= 16; m <<= 1) {
        a0 += __shfl_xor(a0, m); a1 += __shfl_xor(a1, m);
        a2 += __shfl_xor(a2, m); a3 += __shfl_xor(a3, m);
    }
    if (xt < 2) {
        int qb = p * NQ + (r0 << 3) + ((xt & 1) << 2);
        atomicAdd(&pm_sum[qb + 0], a0);
        atomicAdd(&pm_sum[qb + 1], a1);
        atomicAdd(&pm_sum[qb + 2], a2);
        atomicAdd(&pm_sum[qb + 3], a3);
    }
}

// ---------------- K3: build K (64x64), attn (32x42), rearranged weights wbuf[48][48] ----------------
__global__ __launch_bounds__(256) void k_small(const float* __restrict__ pm_sum,
                                               const float* __restrict__ gap_sum,
                                               const float* __restrict__ sigx,
                                               const float* __restrict__ sigy,
                                               const float* __restrict__ opac,
                                               const float* __restrict__ rho,
                                               const float* __restrict__ w_v2,
                                               const float* __restrict__ w_fine,
                                               const float* __restrict__ w_res,
                                               float* __restrict__ Kmat,
                                               float* __restrict__ attn,
                                               float* __restrict__ wbuf) {
    int tid = threadIdx.x;
    if (tid < 64) {
        int q = tid;
        float wsx = 0.f, wsy = 0.f, wop = 0.f, wr = 0.f;
        for (int p = 0; p < NP; ++p) {
            float pv = pm_sum[p * NQ + q] * (1.f / 8192.f);
            wsx += sigx[p] * pv;
            wsy += sigy[p] * pv;
            wop += opac[p] * pv;
            wr  += rho[p]  * pv;
        }
        float a = wsx * wsx, d = wsy * wsy, bc = wr * wsx * wsy;
        float det = a * d - bc * bc;
        float i00 = d / det, i01 = -bc / det, i11 = a / det;
        int iq = q >> 3, jq = q & 7;
        for (int h = 0; h < 8; ++h)
            for (int w = 0; w < 8; ++w) {
                int ki = h - iq + 2, kj = w - jq + 2;
                float val = 0.f;
                if (ki >= 0 && ki < 5 && kj >= 0 && kj < 5) {
                    float xx = -5.f + 2.5f * ki, yy = -5.f + 2.5f * kj;
                    val = wop * __expf(-0.5f * (i00 * xx * xx + 2.f * i01 * xx * yy + i11 * yy * yy));
                }
                Kmat[(q << 6) + (h << 3) + w] = val;
            }
    }
    for (int i = tid; i < NBATCH * LRC; i += 256) {
        int b = i / LRC, co = i % LRC;
        float s = 0.f;
        for (int ci = 0; ci < LRC; ++ci) s += w_v2[co * LRC + ci] * gap_sum[b * LRC + ci];
        s *= (1.f / 16384.f);
        attn[i] = 1.f / (1.f + __expf(-s));
    }
    for (int i = tid; i < NFEAT * 48; i += 256) {
        int c = i / 48, j = i - c * 48;
        float v = 0.f;
        if (j < 36) v = w_fine[(j / 9) * (NFEAT * 9) + c * 9 + (j % 9)];
        else if (j < 40) v = w_res[(j - 36) * NFEAT + c];
        wbuf[i] = v;
    }
}

// ---------------- K4: hr = (colors @ K) * V1 ----------------
__global__ __launch_bounds__(256) void k_hr(const float* __restrict__ feat,
                                            const float* __restrict__ V,
                                            const float* __restrict__ Kmat,
                                            float* __restrict__ hrbuf) {
    __shared__ __align__(16) float lK[4096];          // [q][pos] packed; reads broadcast
    __shared__ __align__(16) float lF[2 * 16 * 128];
    int bid = blockIdx.x;
    int b   = bid / 24;
    int r   = bid - b * 24;
    int strip = r / 3;
    int ch  = (r - strip * 3) * 2;
    int y0  = strip << 4;
    int tid = threadIdx.x;
    {
        const float4* ks = (const float4*)Kmat;
        float4* kd = (float4*)lK;
        for (int i = tid; i < 1024; i += 256) kd[i] = ks[i];
        float4* fd = (float4*)lF;
        const float* fb = feat + (((size_t)b * NFEAT + ch) << 14) + (y0 << 7);
        for (int i = tid; i < 1024; i += 256) {
            int c = i >> 9, rem = i & 511;
            fd[i] = *(const float4*)&fb[((size_t)c << 14) + (rem << 2)];
        }
    }
    __syncthreads();
    int tile = tid >> 3, hrow = tid & 7;
    int tr = tile >> 4, tx = tile & 15;
    float acc[2][8];
#pragma unroll
    for (int c = 0; c < 2; ++c)
#pragma unroll
        for (int j = 0; j < 8; ++j) acc[c][j] = 0.f;
    int fbase = (tr << 3) * 128 + (tx << 3);
    for (int q = 0; q < 64; ++q) {
        int iq = q >> 3, jq = q & 7;
        const float4 k0 = *(const float4*)&lK[(q << 6) + (hrow << 3)];
        const float4 k1 = *(const float4*)&lK[(q << 6) + (hrow << 3) + 4];
#pragma unroll
        for (int c = 0; c < 2; ++c) {
            float col = lF[(c << 11) + fbase + (iq << 7) + jq];
            acc[c][0] += col * k0.x; acc[c][1] += col * k0.y;
            acc[c][2] += col * k0.z; acc[c][3] += col * k0.w;
            acc[c][4] += col * k1.x; acc[c][5] += col * k1.y;
            acc[c][6] += col * k1.z; acc[c][7] += col * k1.w;
        }
    }
    int y = y0 + (tr << 3) + hrow;
#pragma unroll
    for (int c = 0; c < 2; ++c) {
        const float4* vp = (const float4*)(V + (((size_t)b * NFEAT + ch + c) << 14) + ((size_t)y << 7) + (tx << 3));
        float4 v0 = vp[0], v1 = vp[1];
        float4 r0, r1;
        r0.x = acc[c][0] * v0.x; r0.y = acc[c][1] * v0.y; r0.z = acc[c][2] * v0.z; r0.w = acc[c][3] * v0.w;
        r1.x = acc[c][4] * v1.x; r1.y = acc[c][5] * v1.y; r1.z = acc[c][6] * v1.z; r1.w = acc[c][7] * v1.w;
        float4* op = (float4*)(hrbuf + (((size_t)b * C1c + ch + c) << 14) + ((size_t)y << 7) + (tx << 3));
        op[0] = r0; op[1] = r1;
    }
}

// ---------------- K5: conv3x3 (RMW onto base), 2 wave-groups, no spill config ----------------
#define CCH 8
__global__ __launch_bounds__(512, 4) void k_conv(const float* __restrict__ feat,
                                                 const float* __restrict__ V,
                                                 const float* __restrict__ wbuf,
                                                 const float* __restrict__ hrbuf,
                                                 const float* __restrict__ attn,
                                                 float* __restrict__ out) {
    __shared__ float s_in[CCH][18 * 40];   // lds row = input row + 1; lds col = input col + 4
    int bid0 = blockIdx.x;
    int rid  = (bid0 & 7) * 128 + (bid0 >> 3);    // bijective XCD swizzle (1024 = 8*128)
    int b    = rid >> 5;
    int t32  = rid & 31;
    int ty0  = (t32 >> 2) << 4;
    int tx0  = (t32 & 3) << 5;
    int tid  = threadIdx.x;               // 0..511
    int grpu = __builtin_amdgcn_readfirstlane(tid >> 8);   // 0/1, wave-uniform -> scalar
    int ct   = tid & 255;
    int rp   = ct >> 5;                   // 0..7 (row pair)
    int j    = ct & 31;                   // col 0..31
    int gx   = tx0 + j;
    int gy0  = ty0 + 2 * rp;
    int cbase = (2 * rp) * 40 + 3 + j;    // tap base: lds row 2rp = input row 2rp-1

    // staging own pixel (1 px per thread over the 16x32 tile)
    int srow = tid >> 5, scol = tid & 31;
    int sg = ((ty0 + srow) << 7) + tx0 + scol;
    int sl = (srow + 1) * 40 + 4 + scol;

    // halo ring: 100 positions
    bool hhas = tid < 100;
    int rr, cc;
    if (tid < 34)      { rr = 0;        cc = tid; }
    else if (tid < 68) { rr = 17;       cc = tid - 34; }
    else if (tid < 84) { rr = tid - 67; cc = 0; }
    else               { rr = tid - 83; cc = 33; }
    int hsy = ty0 - 1 + rr, hsx = tx0 - 1 + cc;
    float hfm = (hsy >= 0 && hsy < HH && hsx >= 0 && hsx < WW) ? 1.f : 0.f;
    int hoff = (min(HH - 1, max(0, hsy)) << 7) + min(WW - 1, max(0, hsx));
    int hlds = rr * 40 + 3 + cc;

    const float* atb = attn + b * LRC;
    float a0[4] = {0.f, 0.f, 0.f, 0.f};   // conv partial, row gy0
    float a1[4] = {0.f, 0.f, 0.f, 0.f};   // conv partial, row gy0+1

    for (int cb = 0; cb < NFEAT; cb += CCH) {
        __syncthreads();
        // ---- stage 8 channels, 1 px each + halo ----
        for (int k = 0; k < CCH; ++k) {
            int c = cb + k;
            if (c < C1c) {
                const float* hsrc = hrbuf + (((size_t)b * C1c + c) << 14);
                s_in[k][sl] = hsrc[sg];
                if (hhas) s_in[k][hlds] = hsrc[hoff] * hfm;
            } else {
                float am = atb[c - C1c];
                const float* fsrc = feat + (((size_t)b * NFEAT + c) << 14);
                const float* vsrc = V    + (((size_t)b * NFEAT + c) << 14);
                s_in[k][sl] = fsrc[sg] * vsrc[sg] * am;
                if (hhas) s_in[k][hlds] = fsrc[hoff] * vsrc[hoff] * (am * hfm);
            }
        }
        __syncthreads();
        // ---- compute: this group's 4 channels ----
        for (int k = 0; k < 4; ++k) {
            int slot = 4 * grpu + k;
            int c = cb + slot;
            const float* wc = wbuf + c * 48;                  // scalar -> s_load
            float t00 = s_in[slot][cbase],       t01 = s_in[slot][cbase + 1],   t02 = s_in[slot][cbase + 2];
            float t10 = s_in[slot][cbase + 40],  t11 = s_in[slot][cbase + 41],  t12 = s_in[slot][cbase + 42];
            float t20 = s_in[slot][cbase + 80],  t21 = s_in[slot][cbase + 81],  t22 = s_in[slot][cbase + 82];
            float t30 = s_in[slot][cbase + 120], t31 = s_in[slot][cbase + 121], t32 = s_in[slot][cbase + 122];
#pragma unroll
            for (int o = 0; o < 4; ++o) {
                float w0 = wc[o * 9 + 0], w1 = wc[o * 9 + 1], w2 = wc[o * 9 + 2];
                float w3 = wc[o * 9 + 3], w4 = wc[o * 9 + 4], w5 = wc[o * 9 + 5];
                float w6 = wc[o * 9 + 6], w7 = wc[o * 9 + 7], w8 = wc[o * 9 + 8];
                a0[o] += w0 * t00 + w1 * t01 + w2 * t02
                       + w3 * t10 + w4 * t11 + w5 * t12
                       + w6 * t20 + w7 * t21 + w8 * t22;
                a1[o] += w0 * t10 + w1 * t11 + w2 * t12
                       + w3 * t20 + w4 * t21 + w5 * t22
                       + w6 * t30 + w7 * t31 + w8 * t32;
            }
        }
    }
    // ---- merge group1 -> group0, then RMW stores (group0 only) ----
    __syncthreads();
    float* sm = &s_in[0][0];                     // reuse LDS (2048 floats needed)
    int p0 = (2 * rp) * 32 + j, p1 = p0 + 32;
    if (grpu == 1) {
#pragma unroll
        for (int o = 0; o < 4; ++o) { sm[o * 512 + p0] = a0[o]; sm[o * 512 + p1] = a1[o]; }
    }
    __syncthreads();
    if (grpu == 0) {
#pragma unroll
        for (int o = 0; o < 4; ++o) {
            size_t obase = ((size_t)(b * 4 + o)) << 14;
            float* op0 = out + obase + (gy0 << 7) + gx;
            float* op1 = out + obase + ((gy0 + 1) << 7) + gx;
            *op0 = *op0 + a0[o] + sm[o * 512 + p0];
            *op1 = *op1 + a1[o] + sm[o * 512 + p1];
        }
    }
}

extern "C" void kernel_launch(void* const* d_in, const int* in_sizes, int n_in,
                              void* d_out, int out_size, void* d_ws, size_t ws_size,
                              hipStream_t stream) {
    (void)in_sizes; (void)n_in; (void)out_size; (void)ws_size;
    const float* ms     = (const float*)d_in[0];
    const float* feat   = (const float*)d_in[1];
    const float* V      = (const float*)d_in[2];
    const float* logits = (const float*)d_in[3];
    const float* sigx   = (const float*)d_in[4];
    const float* sigy   = (const float*)d_in[5];
    const float* opac   = (const float*)d_in[6];
    const float* rho    = (const float*)d_in[7];
    const float* w_v2   = (const float*)d_in[8];
    const float* w_fine = (const float*)d_in[9];
    const float* b_fine = (const float*)d_in[10];
    const float* w_res  = (const float*)d_in[11];
    const float* b_res  = (const float*)d_in[12];
    float* ws  = (float*)d_ws;
    float* out = (float*)d_out;
    float* inv = ws + OFF_HR;   // disjoint lifetime with hrbuf (consumed by sm2 before k_hr)

    // zero pm_sum + gap
    hipMemsetAsync(ws + OFF_PM, 0, (size_t)(NP * NQ + NBATCH * LRC) * sizeof(float), stream);
    k_phase1<<<512 + 512, 256, 0, stream>>>(logits, feat, ms, w_res, b_fine, b_res,
                                            inv, ws + OFF_GAP, out);
    k_sm2<<<NBATCH * NP, 256, 0, stream>>>(logits, inv, ws + OFF_PM);
    k_small<<<1, 256, 0, stream>>>(ws + OFF_PM, ws + OFF_GAP, sigx, sigy, opac, rho, w_v2,
                                   w_fine, w_res, ws + OFF_K, ws + OFF_ATTN, ws + OFF_WB);
    k_hr<<<768, 256, 0, stream>>>(feat, V, ws + OFF_K, ws + OFF_HR);
    k_conv<<<1024, 512, 0, stream>>>(feat, V, ws + OFF_WB, ws + OFF_HR, ws + OFF_ATTN, out);
}

// Round 14
// 196.318 us; speedup vs baseline: 1.9478x; 1.2483x over previous
//
#include <hip/hip_runtime.h>

#define NBATCH 32
#define NFEAT 48
#define C1c 6
#define LRC 42
#define HH 128
#define WW 128
#define HWSZ 16384
#define NP 81
#define NQ 64

// workspace layout (in floats)
#define OFF_PM   0                      // 81*64 = 5184
#define OFF_GAP  5184                   // 32*42 = 1344  (contiguous after PM -> one memset)
#define OFF_K    6528                   // 64*64 = 4096
#define OFF_ATTN 10624                  // 1344
#define OFF_WB   11968                  // 48*48 = 2304 rearranged weights
#define OFF_HR   14272                  // 32*6*16384 = 3145728
// inv denominators (524288 floats) reuse the OFF_HR region: consumed by k_sm2 BEFORE k_hr writes.

// ---------------- Phase 1 (heterogeneous): A) softmax denominators  B) gap + 1x1 base + up(ms) ----
__global__ __launch_bounds__(256) void k_phase1(const float* __restrict__ logits,
                                                const float* __restrict__ feat,
                                                const float* __restrict__ ms,
                                                const float* __restrict__ w_res,
                                                const float* __restrict__ b_fine,
                                                const float* __restrict__ b_res,
                                                float* __restrict__ invbuf,
                                                float* __restrict__ gap,
                                                float* __restrict__ out) {
    int bid = blockIdx.x;
    int tid = threadIdx.x;
    if (bid < 512) {
        // ---- A: softmax denominators. 9 loads batched in a static float4[9] -> 9 in flight ----
        int idx = bid * 256 + tid;                    // 0..131071 (float4 index)
        int b   = idx >> 12;                          // 4096 float4 per image
        int pos = (idx & 4095) << 2;
        const float* base = logits + (((size_t)b * NP) << 14) + pos;
        float s0 = 0.f, s1 = 0.f, s2 = 0.f, s3 = 0.f;
        for (int g = 0; g < 9; ++g) {
            float4 v[9];
#pragma unroll
            for (int u = 0; u < 9; ++u)
                v[u] = *(const float4*)&base[(size_t)(9 * g + u) << 14];
#pragma unroll
            for (int u = 0; u < 9; ++u) {
                s0 += __expf(v[u].x); s1 += __expf(v[u].y);
                s2 += __expf(v[u].z); s3 += __expf(v[u].w);
            }
        }
        *(float4*)&invbuf[(size_t)idx << 2] =
            make_float4(1.f / s0, 1.f / s1, 1.f / s2, 1.f / s3);
    } else {
        // ---- B: gap sums + 1x1 base + biases + up(ms) -> out (4 px/thread) ----
        int gid = bid - 512;                          // 0..511
        int b = gid >> 4, strip = gid & 15;
        int row = (strip << 3) + (tid >> 5);
        int x0  = (tid & 31) << 2;
        int poff = (row << 7) + x0;
        int lane = tid & 63;
        const float* fb = feat + (((size_t)b * NFEAT) << 14);
        float a[4][4];
#pragma unroll
        for (int j = 0; j < 4; ++j)
#pragma unroll
            for (int o = 0; o < 4; ++o) a[j][o] = 0.f;
        for (int c = 0; c < NFEAT; ++c) {
            float4 f = *(const float4*)&fb[((size_t)c << 14) + poff];
            float wr0 = w_res[c], wr1 = w_res[NFEAT + c];
            float wr2 = w_res[2 * NFEAT + c], wr3 = w_res[3 * NFEAT + c];
            a[0][0] += wr0 * f.x; a[0][1] += wr1 * f.x; a[0][2] += wr2 * f.x; a[0][3] += wr3 * f.x;
            a[1][0] += wr0 * f.y; a[1][1] += wr1 * f.y; a[1][2] += wr2 * f.y; a[1][3] += wr3 * f.y;
            a[2][0] += wr0 * f.z; a[2][1] += wr1 * f.z; a[2][2] += wr2 * f.z; a[2][3] += wr3 * f.z;
            a[3][0] += wr0 * f.w; a[3][1] += wr1 * f.w; a[3][2] += wr2 * f.w; a[3][3] += wr3 * f.w;
            if (c >= C1c) {
                float s = (f.x + f.y) + (f.z + f.w);
                s += __shfl_xor(s, 1);  s += __shfl_xor(s, 2);  s += __shfl_xor(s, 4);
                s += __shfl_xor(s, 8);  s += __shfl_xor(s, 16); s += __shfl_xor(s, 32);
                if (lane == 0) atomicAdd(&gap[b * LRC + (c - C1c)], s);
            }
        }
        float syf = (row + 0.5f) * 0.25f - 0.5f;
        int y0i = (int)floorf(syf); float fy = syf - (float)y0i;
        int y0c = min(31, max(0, y0i)), y1c = min(31, max(0, y0i + 1));
        float fxv[4]; int x0v[4], x1v[4];
#pragma unroll
        for (int j = 0; j < 4; ++j) {
            float sxf = (x0 + j + 0.5f) * 0.25f - 0.5f;
            int x0i = (int)floorf(sxf);
            fxv[j] = sxf - (float)x0i;
            x0v[j] = min(31, max(0, x0i));
            x1v[j] = min(31, max(0, x0i + 1));
        }
#pragma unroll
        for (int o = 0; o < 4; ++o) {
            const float* mb = ms + ((size_t)(b * 4 + o) << 10);
            float addc = b_fine[o] + b_res[o];
            float res[4];
#pragma unroll
            for (int j = 0; j < 4; ++j) {
                float m00 = mb[(y0c << 5) + x0v[j]], m01 = mb[(y0c << 5) + x1v[j]];
                float m10 = mb[(y1c << 5) + x0v[j]], m11 = mb[(y1c << 5) + x1v[j]];
                float up = (m00 * (1.f - fxv[j]) + m01 * fxv[j]) * (1.f - fy)
                         + (m10 * (1.f - fxv[j]) + m11 * fxv[j]) * fy;
                res[j] = a[j][o] + addc + up;
            }
            *(float4*)&out[(((size_t)(b * 4 + o)) << 14) + poff] =
                make_float4(res[0], res[1], res[2], res[3]);
        }
    }
}

// ---------------- K1b: binning pass -> pm_sum[81][64] ----------------
__global__ __launch_bounds__(256) void k_sm2(const float* __restrict__ logits,
                                             const float* __restrict__ invbuf,
                                             float* __restrict__ pm_sum) {
    int bid = blockIdx.x;                 // b*81 + p
    int b = bid / NP, p = bid - b * NP;
    const float* base = logits + ((size_t)(b * NP + p) << 14);
    const float* ib   = invbuf + ((size_t)b << 14);
    int tid = threadIdx.x;
    int r0 = tid >> 5, xt = tid & 31;
    float a0 = 0.f, a1 = 0.f, a2 = 0.f, a3 = 0.f;
    int off = (r0 << 7) + (xt << 2);
#pragma unroll 4
    for (int k = 0; k < 16; ++k) {
        int o2 = off + k * 1024;
        float4 l4 = *(const float4*)&base[o2];
        float4 i4 = *(const float4*)&ib[o2];
        a0 += __expf(l4.x) * i4.x;
        a1 += __expf(l4.y) * i4.y;
        a2 += __expf(l4.z) * i4.z;
        a3 += __expf(l4.w) * i4.w;
    }
#pragma unroll
    for (int m = 2; m <= 16; m <<= 1) {
        a0 += __shfl_xor(a0, m); a1 += __shfl_xor(a1, m);
        a2 += __shfl_xor(a2, m); a3 += __shfl_xor(a3, m);
    }
    if (xt < 2) {
        int qb = p * NQ + (r0 << 3) + ((xt & 1) << 2);
        atomicAdd(&pm_sum[qb + 0], a0);
        atomicAdd(&pm_sum[qb + 1], a1);
        atomicAdd(&pm_sum[qb + 2], a2);
        atomicAdd(&pm_sum[qb + 3], a3);
    }
}

// ---------------- K3: build K (64x64), attn (32x42), rearranged weights wbuf[48][48] ----------------
__global__ __launch_bounds__(256) void k_small(const float* __restrict__ pm_sum,
                                               const float* __restrict__ gap_sum,
                                               const float* __restrict__ sigx,
                                               const float* __restrict__ sigy,
                                               const float* __restrict__ opac,
                                               const float* __restrict__ rho,
                                               const float* __restrict__ w_v2,
                                               const float* __restrict__ w_fine,
                                               const float* __restrict__ w_res,
                                               float* __restrict__ Kmat,
                                               float* __restrict__ attn,
                                               float* __restrict__ wbuf) {
    int tid = threadIdx.x;
    if (tid < 64) {
        int q = tid;
        float wsx = 0.f, wsy = 0.f, wop = 0.f, wr = 0.f;
        for (int p = 0; p < NP; ++p) {
            float pv = pm_sum[p * NQ + q] * (1.f / 8192.f);
            wsx += sigx[p] * pv;
            wsy += sigy[p] * pv;
            wop += opac[p] * pv;
            wr  += rho[p]  * pv;
        }
        float a = wsx * wsx, d = wsy * wsy, bc = wr * wsx * wsy;
        float det = a * d - bc * bc;
        float i00 = d / det, i01 = -bc / det, i11 = a / det;
        int iq = q >> 3, jq = q & 7;
        for (int h = 0; h < 8; ++h)
            for (int w = 0; w < 8; ++w) {
                int ki = h - iq + 2, kj = w - jq + 2;
                float val = 0.f;
                if (ki >= 0 && ki < 5 && kj >= 0 && kj < 5) {
                    float xx = -5.f + 2.5f * ki, yy = -5.f + 2.5f * kj;
                    val = wop * __expf(-0.5f * (i00 * xx * xx + 2.f * i01 * xx * yy + i11 * yy * yy));
                }
                Kmat[(q << 6) + (h << 3) + w] = val;
            }
    }
    for (int i = tid; i < NBATCH * LRC; i += 256) {
        int b = i / LRC, co = i % LRC;
        float s = 0.f;
        for (int ci = 0; ci < LRC; ++ci) s += w_v2[co * LRC + ci] * gap_sum[b * LRC + ci];
        s *= (1.f / 16384.f);
        attn[i] = 1.f / (1.f + __expf(-s));
    }
    for (int i = tid; i < NFEAT * 48; i += 256) {
        int c = i / 48, j = i - c * 48;
        float v = 0.f;
        if (j < 36) v = w_fine[(j / 9) * (NFEAT * 9) + c * 9 + (j % 9)];
        else if (j < 40) v = w_res[(j - 36) * NFEAT + c];
        wbuf[i] = v;
    }
}

// ---------------- K4: hr = (colors @ K) * V1 ----------------
__global__ __launch_bounds__(256) void k_hr(const float* __restrict__ feat,
                                            const float* __restrict__ V,
                                            const float* __restrict__ Kmat,
                                            float* __restrict__ hrbuf) {
    __shared__ __align__(16) float lK[4096];          // [q][pos] packed; reads broadcast
    __shared__ __align__(16) float lF[2 * 16 * 128];
    int bid = blockIdx.x;
    int b   = bid / 24;
    int r   = bid - b * 24;
    int strip = r / 3;
    int ch  = (r - strip * 3) * 2;
    int y0  = strip << 4;
    int tid = threadIdx.x;
    {
        const float4* ks = (const float4*)Kmat;
        float4* kd = (float4*)lK;
        for (int i = tid; i < 1024; i += 256) kd[i] = ks[i];
        float4* fd = (float4*)lF;
        const float* fb = feat + (((size_t)b * NFEAT + ch) << 14) + (y0 << 7);
        for (int i = tid; i < 1024; i += 256) {
            int c = i >> 9, rem = i & 511;
            fd[i] = *(const float4*)&fb[((size_t)c << 14) + (rem << 2)];
        }
    }
    __syncthreads();
    int tile = tid >> 3, hrow = tid & 7;
    int tr = tile >> 4, tx = tile & 15;
    float acc[2][8];
#pragma unroll
    for (int c = 0; c < 2; ++c)
#pragma unroll
        for (int j = 0; j < 8; ++j) acc[c][j] = 0.f;
    int fbase = (tr << 3) * 128 + (tx << 3);
    for (int q = 0; q < 64; ++q) {
        int iq = q >> 3, jq = q & 7;
        const float4 k0 = *(const float4*)&lK[(q << 6) + (hrow << 3)];
        const float4 k1 = *(const float4*)&lK[(q << 6) + (hrow << 3) + 4];
#pragma unroll
        for (int c = 0; c < 2; ++c) {
            float col = lF[(c << 11) + fbase + (iq << 7) + jq];
            acc[c][0] += col * k0.x; acc[c][1] += col * k0.y;
            acc[c][2] += col * k0.z; acc[c][3] += col * k0.w;
            acc[c][4] += col * k1.x; acc[c][5] += col * k1.y;
            acc[c][6] += col * k1.z; acc[c][7] += col * k1.w;
        }
    }
    int y = y0 + (tr << 3) + hrow;
#pragma unroll
    for (int c = 0; c < 2; ++c) {
        const float4* vp = (const float4*)(V + (((size_t)b * NFEAT + ch + c) << 14) + ((size_t)y << 7) + (tx << 3));
        float4 v0 = vp[0], v1 = vp[1];
        float4 r0, r1;
        r0.x = acc[c][0] * v0.x; r0.y = acc[c][1] * v0.y; r0.z = acc[c][2] * v0.z; r0.w = acc[c][3] * v0.w;
        r1.x = acc[c][4] * v1.x; r1.y = acc[c][5] * v1.y; r1.z = acc[c][6] * v1.z; r1.w = acc[c][7] * v1.w;
        float4* op = (float4*)(hrbuf + (((size_t)b * C1c + ch + c) << 14) + ((size_t)y << 7) + (tx << 3));
        op[0] = r0; op[1] = r1;
    }
}

// ---------------- K5: conv3x3 (RMW onto base), double-buffered LDS + reg-staged prefetch ----
// Chunks of 6 with UNIFORM source per chunk: chunk 0 = hr copy, chunks 1..7 = feat*V*attn.
// Per iteration: barrier -> issue next chunk's loads -> compute current -> write regs->LDS^1.
#define CHN 6
__global__ __launch_bounds__(512, 4) void k_conv(const float* __restrict__ feat,
                                                 const float* __restrict__ V,
                                                 const float* __restrict__ wbuf,
                                                 const float* __restrict__ hrbuf,
                                                 const float* __restrict__ attn,
                                                 float* __restrict__ out) {
    __shared__ float s_in[2][CHN][18 * 40];   // 34.5 KB
    int bid0 = blockIdx.x;
    int rid  = (bid0 & 7) * 128 + (bid0 >> 3);    // bijective XCD swizzle (1024 = 8*128)
    int b    = rid >> 5;
    int t32  = rid & 31;
    int ty0  = (t32 >> 2) << 4;
    int tx0  = (t32 & 3) << 5;
    int tid  = threadIdx.x;               // 0..511
    int grpu = __builtin_amdgcn_readfirstlane(tid >> 8);   // 0/1, wave-uniform
    int ct   = tid & 255;
    int rp   = ct >> 5;                   // 0..7 (row pair)
    int j    = ct & 31;                   // col 0..31
    int gx   = tx0 + j;
    int gy0  = ty0 + 2 * rp;
    int cbase = (2 * rp) * 40 + 3 + j;

    // staging own pixel (1 px per thread over the 16x32 tile)
    int srow = tid >> 5, scol = tid & 31;
    int sg = ((ty0 + srow) << 7) + tx0 + scol;
    int sl = (srow + 1) * 40 + 4 + scol;

    // halo ring: 100 positions
    bool hhas = tid < 100;
    int rr, cc;
    if (tid < 34)      { rr = 0;        cc = tid; }
    else if (tid < 68) { rr = 17;       cc = tid - 34; }
    else if (tid < 84) { rr = tid - 67; cc = 0; }
    else               { rr = tid - 83; cc = 33; }
    int hsy = ty0 - 1 + rr, hsx = tx0 - 1 + cc;
    float hfm = (hsy >= 0 && hsy < HH && hsx >= 0 && hsx < WW) ? 1.f : 0.f;
    int hoff = (min(HH - 1, max(0, hsy)) << 7) + min(WW - 1, max(0, hsx));
    int hlds = rr * 40 + 3 + cc;

    const float* atb = attn + b * LRC;
    float a0[4] = {0.f, 0.f, 0.f, 0.f};
    float a1[4] = {0.f, 0.f, 0.f, 0.f};
    float rA[CHN], rB[CHN], rHA[CHN], rHB[CHN], amv[CHN];

    // ---- prologue: chunk 0 = hr channels 0..5 (pure copy) ----
#pragma unroll
    for (int k = 0; k < CHN; ++k) {
        const float* hs = hrbuf + (((size_t)(b * C1c + k)) << 14);
        rA[k]  = hs[sg];
        rHA[k] = hhas ? hs[hoff] : 0.f;
    }
#pragma unroll
    for (int k = 0; k < CHN; ++k) {
        s_in[0][k][sl] = rA[k];
        if (hhas) s_in[0][k][hlds] = rHA[k] * hfm;
    }
    int cur = 0;
    for (int t = 0; t < 8; ++t) {
        __syncthreads();
        // ---- issue next chunk's loads (channels 6(t+1)..6(t+1)+5, always feat*V) ----
        if (t < 7) {
            int c0 = CHN * (t + 1);
#pragma unroll
            for (int k = 0; k < CHN; ++k) {
                int c = c0 + k;
                const float* fs = feat + (((size_t)(b * NFEAT + c)) << 14);
                const float* vs = V    + (((size_t)(b * NFEAT + c)) << 14);
                rA[k] = fs[sg];
                rB[k] = vs[sg];
                amv[k] = atb[c - C1c];
                rHA[k] = hhas ? fs[hoff] : 0.f;
                rHB[k] = hhas ? vs[hoff] : 0.f;
            }
        }
        // ---- compute current chunk (hides the loads above) ----
        int c0c = CHN * t;
        for (int k = 0; k < 3; ++k) {
            int slot = 3 * grpu + k;
            int c = c0c + slot;
            const float* wc = wbuf + c * 48;          // uniform -> s_load
            const float* sp = &s_in[cur][slot][cbase];
            float t00 = sp[0],   t01 = sp[1],   t02 = sp[2];
            float t10 = sp[40],  t11 = sp[41],  t12 = sp[42];
            float t20 = sp[80],  t21 = sp[81],  t22 = sp[82];
            float t30 = sp[120], t31 = sp[121], t32 = sp[122];
#pragma unroll
            for (int o = 0; o < 4; ++o) {
                float w0 = wc[o * 9 + 0], w1 = wc[o * 9 + 1], w2 = wc[o * 9 + 2];
                float w3 = wc[o * 9 + 3], w4 = wc[o * 9 + 4], w5 = wc[o * 9 + 5];
                float w6 = wc[o * 9 + 6], w7 = wc[o * 9 + 7], w8 = wc[o * 9 + 8];
                a0[o] += w0 * t00 + w1 * t01 + w2 * t02
                       + w3 * t10 + w4 * t11 + w5 * t12
                       + w6 * t20 + w7 * t21 + w8 * t22;
                a1[o] += w0 * t10 + w1 * t11 + w2 * t12
                       + w3 * t20 + w4 * t21 + w5 * t22
                       + w6 * t30 + w7 * t31 + w8 * t32;
            }
        }
        // ---- write prefetched chunk to the other buffer ----
        if (t < 7) {
            int nxt = cur ^ 1;
#pragma unroll
            for (int k = 0; k < CHN; ++k) {
                s_in[nxt][k][sl] = rA[k] * rB[k] * amv[k];
                if (hhas) s_in[nxt][k][hlds] = rHA[k] * rHB[k] * (amv[k] * hfm);
            }
        }
        cur ^= 1;
    }
    // ---- merge group1 -> group0, then RMW stores (group0 only) ----
    __syncthreads();
    float* sm = &s_in[0][0][0];                  // reuse LDS (2048 floats needed)
    int p0 = (2 * rp) * 32 + j, p1 = p0 + 32;
    if (grpu == 1) {
#pragma unroll
        for (int o = 0; o < 4; ++o) { sm[o * 512 + p0] = a0[o]; sm[o * 512 + p1] = a1[o]; }
    }
    __syncthreads();
    if (grpu == 0) {
#pragma unroll
        for (int o = 0; o < 4; ++o) {
            size_t obase = ((size_t)(b * 4 + o)) << 14;
            float* op0 = out + obase + (gy0 << 7) + gx;
            float* op1 = out + obase + ((gy0 + 1) << 7) + gx;
            *op0 = *op0 + a0[o] + sm[o * 512 + p0];
            *op1 = *op1 + a1[o] + sm[o * 512 + p1];
        }
    }
}

extern "C" void kernel_launch(void* const* d_in, const int* in_sizes, int n_in,
                              void* d_out, int out_size, void* d_ws, size_t ws_size,
                              hipStream_t stream) {
    (void)in_sizes; (void)n_in; (void)out_size; (void)ws_size;
    const float* ms     = (const float*)d_in[0];
    const float* feat   = (const float*)d_in[1];
    const float* V      = (const float*)d_in[2];
    const float* logits = (const float*)d_in[3];
    const float* sigx   = (const float*)d_in[4];
    const float* sigy   = (const float*)d_in[5];
    const float* opac   = (const float*)d_in[6];
    const float* rho    = (const float*)d_in[7];
    const float* w_v2   = (const float*)d_in[8];
    const float* w_fine = (const float*)d_in[9];
    const float* b_fine = (const float*)d_in[10];
    const float* w_res  = (const float*)d_in[11];
    const float* b_res  = (const float*)d_in[12];
    float* ws  = (float*)d_ws;
    float* out = (float*)d_out;
    float* inv = ws + OFF_HR;   // disjoint lifetime with hrbuf (consumed by sm2 before k_hr)

    // zero pm_sum + gap
    hipMemsetAsync(ws + OFF_PM, 0, (size_t)(NP * NQ + NBATCH * LRC) * sizeof(float), stream);
    k_phase1<<<512 + 512, 256, 0, stream>>>(logits, feat, ms, w_res, b_fine, b_res,
                                            inv, ws + OFF_GAP, out);
    k_sm2<<<NBATCH * NP, 256, 0, stream>>>(logits, inv, ws + OFF_PM);
    k_small<<<1, 256, 0, stream>>>(ws + OFF_PM, ws + OFF_GAP, sigx, sigy, opac, rho, w_v2,
                                   w_fine, w_res, ws + OFF_K, ws + OFF_ATTN, ws + OFF_WB);
    k_hr<<<768, 256, 0, stream>>>(feat, V, ws + OFF_K, ws + OFF_HR);
    k_conv<<<1024, 512, 0, stream>>>(feat, V, ws + OFF_WB, ws + OFF_HR, ws + OFF_ATTN, out);
}